// Round 11
// baseline (563.613 us; speedup 1.0000x reference)
//
#include <hip/hip_runtime.h>
#include <stdint.h>

// Problem constants: B=256, T=128, D=256, H=8, AE=32, DFF=512
#define DEVI static __device__ __forceinline__

typedef __attribute__((ext_vector_type(4))) float f32x4;
typedef __attribute__((ext_vector_type(8))) short bf8;     // 8 bf16 (MFMA A/B frag)
typedef __attribute__((ext_vector_type(4))) unsigned short u16x4;
typedef __attribute__((ext_vector_type(4))) unsigned int u32x4;

DEVI unsigned short f2bf(float f) {
  unsigned u = __builtin_bit_cast(unsigned, f);
  u = (u + 0x7FFFu + ((u >> 16) & 1u)) >> 16;
  return (unsigned short)u;
}
DEVI float bf2f(unsigned short s) {
  return __builtin_bit_cast(float, ((unsigned)s) << 16);
}
DEVI unsigned cvt_pk_bf16(float lo, float hi) {
  unsigned r;
  asm("v_cvt_pk_bf16_f32 %0, %1, %2" : "=v"(r) : "v"(lo), "v"(hi));
  return r;
}
// swizzle for 64-B rows (gemm As/Ws, attn vs): 16B granularity, 4 slots
DEVI int swz32(int row) { return (((row >> 1) ^ row) & 3) << 4; }

DEVI void gload16(const void* g, void* l) {
  __builtin_amdgcn_global_load_lds(
      (const __attribute__((address_space(1))) unsigned*)g,
      (__attribute__((address_space(3))) unsigned*)l, 16, 0, 0);
}

// ---------------------------------------------------------------------------
// Per-t batched GEMM: C[b,t, n0+*] = sum_k A[b,t,k] * Wsel[t,k,n]
// 2-phase pipeline (T3): dbuf As via global_load_lds (pre-swizzled source),
// dbuf Ws reg-staged fp32->bf16 cvt_pk, ONE barrier per K-tile, STAGE(next)
// before compute(cur). BM=256, BN=128, BK=32, 8 waves.
// 1-D grid, XCD same-t grouping + two-weight fusion. [= round-8/9/10 PASS]
// ---------------------------------------------------------------------------
template<bool OUT_BF16>
__global__ __launch_bounds__(512, 4)
void gemm_tk(const unsigned short* __restrict__ A, const float* __restrict__ W0,
             const float* __restrict__ W1, void* __restrict__ C,
             int Ka, int N, int lognx, int ldC)
{
  const int j = blockIdx.x;
  const int t = (j & 7) + ((j >> (3 + lognx)) << 3);
  const int nblk = (j >> 3) & ((1 << lognx) - 1);
  const int n0blk = nblk * 128;
  const float* Wsel = (n0blk >= N) ? W1 : W0;
  const int n0w = (n0blk >= N) ? (n0blk - N) : n0blk;

  const int tid = threadIdx.x;
  const int lane = tid & 63;
  const int wv = tid >> 6;        // 0..7
  const int wrow = wv * 32;

  __shared__ short As[2][256 * 32];  // [m][k] 64-B rows, swz32; 2 x 16KB
  __shared__ short Ws[2][128 * 32];  // [n][k] 64-B rows, swz32; 2 x 8KB

  f32x4 acc[2][8];
#pragma unroll
  for (int i = 0; i < 2; ++i)
#pragma unroll
    for (int jj = 0; jj < 8; ++jj) acc[i][jj] = f32x4{0.f, 0.f, 0.f, 0.f};

  const long ldA = 128L * Ka;
  const unsigned short* Ab = A + (long)t * Ka;
  const float* Wb = Wsel + (long)t * Ka * N + n0w;

  const int n0 = (tid & 31) * 4;  // 4 consecutive n per thread (W staging)
  const int kp = tid >> 5;        // k-pair 0..15 (W staging)

  // ---- prologue: stage tile 0 into As[0]/Ws[0]
#pragma unroll
  for (int it = 0; it < 2; ++it) {
    int ci = tid + it * 512;            // 16B chunk id; m=ci>>2
    int m = ci >> 2, cb = (ci & 3) * 16;
    gload16((const char*)(Ab + (long)m * ldA) + (cb ^ swz32(m)),
            (char*)(&As[0][0]) + ci * 16);
  }
  {
    f32x4 wlo = *(const f32x4*)(Wb + (long)(kp * 2) * N + n0);
    f32x4 whi = *(const f32x4*)(Wb + (long)(kp * 2 + 1) * N + n0);
#pragma unroll
    for (int jj = 0; jj < 4; ++jj) {
      int n = n0 + jj;
      *(unsigned*)((char*)(&Ws[0][0]) + n * 64 + ((kp * 4) ^ swz32(n))) =
          cvt_pk_bf16(wlo[jj], whi[jj]);
    }
  }

  const int nt = Ka >> 5;
  int cur = 0;
  for (int kt = 0; kt < nt; ++kt) {
    __syncthreads();  // drain: As[cur]/Ws[cur] ready, prior reads of other buf done
    const bool more = (kt + 1) < nt;
    f32x4 wlo, whi;
    if (more) {
      // STAGE(next) first: loads fly during compute, drained at next barrier
      const unsigned short* An = Ab + (kt + 1) * 32;
#pragma unroll
      for (int it = 0; it < 2; ++it) {
        int ci = tid + it * 512;
        int m = ci >> 2, cb = (ci & 3) * 16;
        gload16((const char*)(An + (long)m * ldA) + (cb ^ swz32(m)),
                (char*)(&As[cur ^ 1][0]) + ci * 16);
      }
      const float* Wn = Wb + (long)(kt + 1) * 32 * N;
      wlo = *(const f32x4*)(Wn + (long)(kp * 2) * N + n0);
      whi = *(const f32x4*)(Wn + (long)(kp * 2 + 1) * N + n0);
    }
    // ---- compute tile kt
    const int kb2 = (lane >> 4) * 16;  // k-chunk byte offset
    bf8 a0, a1;
    {
      const int m0 = wrow + (lane & 15);
      const int m1 = m0 + 16;
      a0 = *(const bf8*)((const char*)(&As[cur][0]) + m0 * 64 + (kb2 ^ swz32(m0)));
      a1 = *(const bf8*)((const char*)(&As[cur][0]) + m1 * 64 + (kb2 ^ swz32(m1)));
    }
#pragma unroll
    for (int ni = 0; ni < 8; ++ni) {
      const int n = ni * 16 + (lane & 15);
      bf8 bfr = *(const bf8*)((const char*)(&Ws[cur][0]) + n * 64 + (kb2 ^ swz32(n)));
      acc[0][ni] = __builtin_amdgcn_mfma_f32_16x16x32_bf16(a0, bfr, acc[0][ni], 0, 0, 0);
      acc[1][ni] = __builtin_amdgcn_mfma_f32_16x16x32_bf16(a1, bfr, acc[1][ni], 0, 0, 0);
    }
    if (more) {
#pragma unroll
      for (int jj = 0; jj < 4; ++jj) {
        int n = n0 + jj;
        *(unsigned*)((char*)(&Ws[cur ^ 1][0]) + n * 64 + ((kp * 4) ^ swz32(n))) =
            cvt_pk_bf16(wlo[jj], whi[jj]);
      }
    }
    cur ^= 1;
  }
  // epilogue: C/D layout col=lane&15, row=(lane>>4)*4+reg
#pragma unroll
  for (int mi = 0; mi < 2; ++mi)
#pragma unroll
    for (int ni = 0; ni < 8; ++ni)
#pragma unroll
      for (int r = 0; r < 4; ++r) {
        int m = wrow + mi * 16 + (lane >> 4) * 4 + r;
        int n = n0blk + ni * 16 + (lane & 15);
        long off = ((long)m * 128 + t) * ldC + n;
        float v = acc[mi][ni][r];
        if constexpr (OUT_BF16) reinterpret_cast<unsigned short*>(C)[off] = f2bf(v);
        else reinterpret_cast<float*>(C)[off] = v;
      }
}

// ---------------------------------------------------------------------------
// fp32 -> bf16 convert (X)
// ---------------------------------------------------------------------------
__global__ __launch_bounds__(256)
void cvt_bf(const float* __restrict__ in, unsigned short* __restrict__ out, long n)
{
  long i = ((long)blockIdx.x * 256 + threadIdx.x) * 8;
  if (i >= n) return;
  f32x4 a = *reinterpret_cast<const f32x4*>(in + i);
  f32x4 b = *reinterpret_cast<const f32x4*>(in + i + 4);
  u16x4 w0, w1;
#pragma unroll
  for (int j = 0; j < 4; ++j) { w0[j] = f2bf(a[j]); w1[j] = f2bf(b[j]); }
  *reinterpret_cast<u16x4*>(out + i) = w0;
  *reinterpret_cast<u16x4*>(out + i + 4) = w1;
}

// ---------------------------------------------------------------------------
// v (B,T,H*256) -> vT (B*H, 256, 128)   [known-good]
// ---------------------------------------------------------------------------
__global__ __launch_bounds__(256)
void trans_v(const unsigned short* __restrict__ vb, unsigned short* __restrict__ vT)
{
  const int bh = blockIdx.y;
  const int b = bh >> 3, h = bh & 7;
  const int tile = blockIdx.x;   // 0..31
  const int tt = tile >> 3;      // t-tile (4)
  const int td = tile & 7;       // d-tile (8)
  __shared__ unsigned short sm[32][33];
  const int rloc = threadIdx.x >> 3;
  const int q4 = (threadIdx.x & 7) * 4;
  {
    long off = ((long)b * 128 + tt * 32 + rloc) * 2048 + h * 256 + td * 32 + q4;
    u16x4 v = *reinterpret_cast<const u16x4*>(vb + off);
#pragma unroll
    for (int j = 0; j < 4; ++j) sm[rloc][q4 + j] = v[j];
  }
  __syncthreads();
  {
    u16x4 w;
#pragma unroll
    for (int j = 0; j < 4; ++j) w[j] = sm[q4 + j][rloc];
    long off = ((long)bh * 256 + td * 32 + rloc) * 128 + tt * 32 + q4;
    *reinterpret_cast<u16x4*>(vT + off) = w;
  }
}

// ---------------------------------------------------------------------------
// Fused attention for one (b,h). Round 11 (T12 port): SWAPPED QK^T
// (mfma(K,Q) -> D[s][t], lane holds full P-column for t=lane&15) ->
// in-lane softmax (31 ops + shfl_xor 16/32) -> normalized P packed to bf16
// in regs (cvt_pk) -> PV A-frags assembled via __shfl (no ps LDS at all).
// vs staging / vT / barriers / epilogue layout: identical to round 10.
//
// Shfl algebra (derived & element-checked): target lane L (p=L>>4, col=L&15)
// needs A-frag elem j at k-step kst: P[s = kst*32 + p*8 + j][t = wrow+col].
// Source: lane L' = (2(p&1) + (j>>2))*16 + col, value vv[ni'][r'] with
// ni' = 2kst + (p>>1), r' = j&3. Packed pairs pk[ni][h]={r=2h,2h+1} =>
// frag word W[w] (elems j=2w,2w+1) = pk[2kst+(p>>1)][w&1] from
// src lane (2(p&1)+(w>>1))*16+col.
// ---------------------------------------------------------------------------
__global__ __launch_bounds__(512, 4)
void attn_k(const unsigned short* __restrict__ qk, const unsigned short* __restrict__ vT,
            unsigned short* __restrict__ cat)
{
  const int h = blockIdx.x, b = blockIdx.y;
  const int tid = threadIdx.x, lane = tid & 63, wv = tid >> 6;
  const int wrow = wv * 16;          // 16 t-rows per wave

  __shared__ short vs[2][256 * 32];  // vT s-chunk [d][s32] 64-B rows swz32, 2x16KB

  const long qkBase = ((long)b * 128) * 512 + h * 32;
  const long vBase = ((long)(b * 8 + h)) * 256 * 128;
  const int kb_ = (lane >> 4) * 8;

  // stage s-chunk 0 into vs[0] (issue-only; drained at first chunk barrier).
#pragma unroll
  for (int it = 0; it < 2; ++it) {
    int ci = tid + it * 512;
    int d = ci >> 2, sc = ci & 3;
    gload16(vT + vBase + (long)d * 128 + (((sc * 16) ^ swz32(d)) >> 1),
            (char*)(&vs[0][0]) + ci * 16);
  }

  // S^T = K Q^T via swapped MFMA: sacc[ni] = D[s_local][t_local],
  // lane holds col t = wrow + (lane&15), rows s = ni*16 + (lane>>4)*4 + r.
  f32x4 sacc[8];
#pragma unroll
  for (int c = 0; c < 8; ++c) sacc[c] = f32x4{0.f, 0.f, 0.f, 0.f};
  bf8 aq;
  {
    int row = wrow + (lane & 15);
    aq = *reinterpret_cast<const bf8*>(qk + qkBase + (long)row * 512 + kb_);
  }
#pragma unroll
  for (int ni = 0; ni < 8; ++ni) {
    int s = ni * 16 + (lane & 15);
    bf8 bk = *reinterpret_cast<const bf8*>(qk + qkBase + 256 + (long)s * 512 + kb_);
    sacc[ni] = __builtin_amdgcn_mfma_f32_16x16x32_bf16(bk, aq, sacc[ni], 0, 0, 0);  // SWAPPED
  }

  // in-lane softmax over the 32 s-values held per lane; cross-quad reduce
  // via shfl_xor(16)/shfl_xor(32) (quads hold disjoint s-subsets, same t).
  const float scale = 0.17677669529663687f;  // 1/sqrt(32)
  float mx = -1e30f;
#pragma unroll
  for (int ni = 0; ni < 8; ++ni)
#pragma unroll
    for (int r = 0; r < 4; ++r) { sacc[ni][r] *= scale; mx = fmaxf(mx, sacc[ni][r]); }
  mx = fmaxf(mx, __shfl_xor(mx, 16, 64));
  mx = fmaxf(mx, __shfl_xor(mx, 32, 64));
  float s_ = 0.f;
#pragma unroll
  for (int ni = 0; ni < 8; ++ni)
#pragma unroll
    for (int r = 0; r < 4; ++r) { float e = __expf(sacc[ni][r] - mx); sacc[ni][r] = e; s_ += e; }
  s_ += __shfl_xor(s_, 16, 64);
  s_ += __shfl_xor(s_, 32, 64);
  const float sinv = 1.0f / s_;

  // normalized P -> bf16 pairs in registers: pk[ni][h] = {r=2h, r=2h+1}
  unsigned pk[8][2];
#pragma unroll
  for (int ni = 0; ni < 8; ++ni) {
    pk[ni][0] = cvt_pk_bf16(sacc[ni][0] * sinv, sacc[ni][1] * sinv);
    pk[ni][1] = cvt_pk_bf16(sacc[ni][2] * sinv, sacc[ni][3] * sinv);
  }

  // PV over four 32-wide s-chunks, double-buffered LDS (T3 2-phase).
  f32x4 oacc[16];
#pragma unroll
  for (int c = 0; c < 16; ++c) oacc[c] = f32x4{0.f, 0.f, 0.f, 0.f};

  const int p = lane >> 4;
  const int colL = lane & 15;
  const int src0 = (2 * (p & 1) + 0) * 16 + colL;  // for w>>1 == 0
  const int src1 = (2 * (p & 1) + 1) * 16 + colL;  // for w>>1 == 1
  const bool hiSel = (lane & 32) != 0;             // p >= 2

#pragma unroll 1
  for (int cs = 0; cs < 4; ++cs) {
    __syncthreads();  // vs[cs&1] staged (vmcnt drained); cs-1 compute done
    if (cs < 3) {
      // STAGE next chunk into the other buffer; overlaps this chunk's MFMAs
#pragma unroll
      for (int it = 0; it < 2; ++it) {
        int ci = tid + it * 512;
        int d = ci >> 2, sc = ci & 3;
        gload16(vT + vBase + (long)d * 128 + (cs + 1) * 32 + (((sc * 16) ^ swz32(d)) >> 1),
                (char*)(&vs[(cs + 1) & 1][0]) + ci * 16);
      }
    }
    // assemble A-frag for this kst from pk via shfl (see header derivation)
    bf8 ap;
    {
      const int kst = cs;
      unsigned lo0 = __shfl(pk[2 * kst][0], src0, 64);
      unsigned lo1 = __shfl(pk[2 * kst][1], src0, 64);
      unsigned lo2 = __shfl(pk[2 * kst][0], src1, 64);
      unsigned lo3 = __shfl(pk[2 * kst][1], src1, 64);
      unsigned hi0 = __shfl(pk[2 * kst + 1][0], src0, 64);
      unsigned hi1 = __shfl(pk[2 * kst + 1][1], src0, 64);
      unsigned hi2 = __shfl(pk[2 * kst + 1][0], src1, 64);
      unsigned hi3 = __shfl(pk[2 * kst + 1][1], src1, 64);
      u32x4 W;
      W[0] = hiSel ? hi0 : lo0;
      W[1] = hiSel ? hi1 : lo1;
      W[2] = hiSel ? hi2 : lo2;
      W[3] = hiSel ? hi3 : lo3;
      ap = __builtin_bit_cast(bf8, W);
    }
    __builtin_amdgcn_s_setprio(1);
#pragma unroll
    for (int c = 0; c < 16; ++c) {
      int d = c * 16 + (lane & 15);
      bf8 bv = *reinterpret_cast<const bf8*>(
          reinterpret_cast<const char*>(&vs[cs & 1][0]) + d * 64 + ((kb_ * 2) ^ swz32(d)));
      oacc[c] = __builtin_amdgcn_mfma_f32_16x16x32_bf16(ap, bv, oacc[c], 0, 0, 0);
    }
    __builtin_amdgcn_s_setprio(0);
  }

  // write cat[b,t,h*256+d] (P already normalized)
#pragma unroll
  for (int c = 0; c < 16; ++c)
#pragma unroll
    for (int r = 0; r < 4; ++r) {
      int tt = wrow + (lane >> 4) * 4 + r;
      int d = c * 16 + (lane & 15);
      float v = oacc[c][r];
      long off = ((long)b * 128 + tt) * 2048 + h * 256 + d;
      cat[off] = f2bf(v);
    }
}

// ---------------------------------------------------------------------------
// LayerNorm(a+b): a,b read as bf16; write fp32 (WF) and/or bf16 (WB).
// ---------------------------------------------------------------------------
template<bool WF, bool WB>
__global__ __launch_bounds__(256)
void ln_k(const unsigned short* __restrict__ a, const unsigned short* __restrict__ bsrc,
          const float* __restrict__ gamma, const float* __restrict__ beta,
          float* __restrict__ of, unsigned short* __restrict__ ob)
{
  const int row = blockIdx.x * 4 + (threadIdx.x >> 6);
  const int lane = threadIdx.x & 63;
  const long base = (long)row * 256 + lane * 4;
  u16x4 ua = *reinterpret_cast<const u16x4*>(a + base);
  u16x4 ub = *reinterpret_cast<const u16x4*>(bsrc + base);
  f32x4 x;
#pragma unroll
  for (int j = 0; j < 4; ++j) x[j] = bf2f(ua[j]) + bf2f(ub[j]);
  float s = x[0] + x[1] + x[2] + x[3];
  float s2 = x[0] * x[0] + x[1] * x[1] + x[2] * x[2] + x[3] * x[3];
#pragma unroll
  for (int mm = 1; mm < 64; mm <<= 1) { s += __shfl_xor(s, mm, 64); s2 += __shfl_xor(s2, mm, 64); }
  float mean = s * (1.f / 256.f);
  float var = fmaxf(s2 * (1.f / 256.f) - mean * mean, 0.f);
  float inv = rsqrtf(var + 1e-5f);
  f32x4 g = *reinterpret_cast<const f32x4*>(gamma + lane * 4);
  f32x4 be = *reinterpret_cast<const f32x4*>(beta + lane * 4);
  f32x4 y;
#pragma unroll
  for (int j = 0; j < 4; ++j) y[j] = (x[j] - mean) * inv * g[j] + be[j];
  if constexpr (WF) *reinterpret_cast<f32x4*>(of + base) = y;
  if constexpr (WB) {
    u16x4 w;
#pragma unroll
    for (int j = 0; j < 4; ++j) w[j] = f2bf(y[j]);
    *reinterpret_cast<u16x4*>(ob + base) = w;
  }
}

// ---------------------------------------------------------------------------
// hidden = silu(gate) * up, reading the fused gateup buffer.
// ---------------------------------------------------------------------------
__global__ __launch_bounds__(256)
void silu_k(const unsigned short* __restrict__ gu, unsigned short* __restrict__ o, long n)
{
  long i = ((long)blockIdx.x * 256 + threadIdx.x) * 8;
  if (i >= n) return;
  long r = i >> 9;
  int f = (int)(i & 511);
  const unsigned short* g = gu + r * 1024 + f;
  const unsigned short* u = g + 512;
  u16x4 g0 = *reinterpret_cast<const u16x4*>(g);
  u16x4 g1 = *reinterpret_cast<const u16x4*>(g + 4);
  u16x4 u0 = *reinterpret_cast<const u16x4*>(u);
  u16x4 u1 = *reinterpret_cast<const u16x4*>(u + 4);
  u16x4 o0, o1;
#pragma unroll
  for (int j = 0; j < 4; ++j) {
    float gg = bf2f(g0[j]), uu = bf2f(u0[j]);
    o0[j] = f2bf(gg / (1.f + __expf(-gg)) * uu);
    gg = bf2f(g1[j]); uu = bf2f(u1[j]);
    o1[j] = f2bf(gg / (1.f + __expf(-gg)) * uu);
  }
  *reinterpret_cast<u16x4*>(o + i) = o0;
  *reinterpret_cast<u16x4*>(o + i + 4) = o1;
}

// ---------------------------------------------------------------------------
// Workspace (304 MiB, lifetime reuse). All LN-chain intermediates bf16:
//   [0,16) Xb   [16,48) qkb
//   regA @48MiB (128): vb(128) -> cat(128) -> gateup(64)|hid@64(32)
//   regB @176MiB (128): vT(128) -> attnpb@0(16)|x1b@16(16)|ffnb@32(16)
// ---------------------------------------------------------------------------
extern "C" void kernel_launch(void* const* d_in, const int* in_sizes, int n_in,
                              void* d_out, int out_size, void* d_ws, size_t ws_size,
                              hipStream_t stream)
{
  const float* X  = (const float*)d_in[0];
  const float* Qw = (const float*)d_in[1];
  const float* Kw = (const float*)d_in[2];
  const float* Vw = (const float*)d_in[3];
  const float* Ow = (const float*)d_in[4];
  const float* Wg = (const float*)d_in[5];
  const float* Wu = (const float*)d_in[6];
  const float* Wd = (const float*)d_in[7];
  const float* g1 = (const float*)d_in[8];
  const float* b1 = (const float*)d_in[9];
  const float* g2 = (const float*)d_in[10];
  const float* b2 = (const float*)d_in[11];

  char* ws = (char*)d_ws;
  const size_t MiB = 1048576;
  unsigned short* Xb  = (unsigned short*)(ws);
  unsigned short* qkb = (unsigned short*)(ws + 16 * MiB);
  char* regA = ws + 48 * MiB;    // 128 MiB
  char* regB = regA + 128 * MiB; // 128 MiB

  unsigned short* vb     = (unsigned short*)regA;           // dead after trans_v
  unsigned short* vT     = (unsigned short*)regB;           // dead after attn_k
  unsigned short* cat    = (unsigned short*)regA;           // attn out (vb dead)
  unsigned short* attnpb = (unsigned short*)(regB);         // O-proj out bf16 (vT dead)
  unsigned short* x1b    = (unsigned short*)(regB + 16 * MiB);
  unsigned short* ffnb   = (unsigned short*)(regB + 32 * MiB);
  unsigned short* gateup = (unsigned short*)(regA);         // cat dead after O-proj
  unsigned short* hidb   = (unsigned short*)(regA + 64 * MiB);
  float* out = (float*)d_out;

  dim3 blk(256), gblk(512);
  cvt_bf<<<dim3(4096), blk, 0, stream>>>(X, Xb, (long)8388608);
  // Q|K fused: N=256 each, ldC=512, nx=4 (lognx=2) -> 512 blocks
  gemm_tk<true><<<dim3(512), gblk, 0, stream>>>(Xb, Qw, Kw, (void*)qkb, 256, 256, 2, 512);
  // V: nx=16 (lognx=4) -> 2048 blocks
  gemm_tk<true><<<dim3(2048), gblk, 0, stream>>>(Xb, Vw, Vw, (void*)vb, 256, 2048, 4, 2048);
  trans_v<<<dim3(32, 2048), blk, 0, stream>>>(vb, vT);
  attn_k<<<dim3(8, 256), gblk, 0, stream>>>(qkb, vT, cat);
  // O-proj -> bf16: nx=2 (lognx=1) -> 256 blocks
  gemm_tk<true><<<dim3(256), gblk, 0, stream>>>(cat, Ow, Ow, (void*)attnpb, 2048, 256, 1, 256);
  // ln1: x1 = LN(Xb + attnpb) -> x1b only
  ln_k<false, true><<<dim3(8192), blk, 0, stream>>>(Xb, attnpb, g1, b1, (float*)nullptr, x1b);
  // gate|up fused: N=512 each, ldC=1024, nx=8 (lognx=3) -> 1024 blocks
  gemm_tk<true><<<dim3(1024), gblk, 0, stream>>>(x1b, Wg, Wu, (void*)gateup, 256, 512, 3, 1024);
  silu_k<<<dim3(8192), blk, 0, stream>>>(gateup, hidb, (long)16777216);
  // down -> bf16: nx=2 (lognx=1) -> 256 blocks
  gemm_tk<true><<<dim3(256), gblk, 0, stream>>>(hidb, Wd, Wd, (void*)ffnb, 512, 256, 1, 256);
  // ln2: out = LN(x1b + ffnb) -> fp32 d_out
  ln_k<true, false><<<dim3(8192), blk, 0, stream>>>(x1b, ffnb, g2, b2, out, (unsigned short*)nullptr);
}

// Round 12
// 535.234 us; speedup vs baseline: 1.0530x; 1.0530x over previous
//
#include <hip/hip_runtime.h>
#include <stdint.h>

// Problem constants: B=256, T=128, D=256, H=8, AE=32, DFF=512
#define DEVI static __device__ __forceinline__

typedef __attribute__((ext_vector_type(4))) float f32x4;
typedef __attribute__((ext_vector_type(8))) short bf8;     // 8 bf16 (MFMA A/B frag)
typedef __attribute__((ext_vector_type(4))) unsigned short u16x4;

DEVI unsigned short f2bf(float f) {
  unsigned u = __builtin_bit_cast(unsigned, f);
  u = (u + 0x7FFFu + ((u >> 16) & 1u)) >> 16;
  return (unsigned short)u;
}
DEVI float bf2f(unsigned short s) {
  return __builtin_bit_cast(float, ((unsigned)s) << 16);
}
DEVI unsigned cvt_pk_bf16(float lo, float hi) {
  unsigned r;
  asm("v_cvt_pk_bf16_f32 %0, %1, %2" : "=v"(r) : "v"(lo), "v"(hi));
  return r;
}
// swizzle for 256-B rows (attn ps): 16B granularity, 8 slots
DEVI int swz(int row) { return (((row >> 2) ^ row) & 7) << 4; }
// swizzle for 64-B rows (gemm As/Ws, attn vs): 16B granularity, 4 slots
DEVI int swz32(int row) { return (((row >> 1) ^ row) & 3) << 4; }

DEVI void gload16(const void* g, void* l) {
  __builtin_amdgcn_global_load_lds(
      (const __attribute__((address_space(1))) unsigned*)g,
      (__attribute__((address_space(3))) unsigned*)l, 16, 0, 0);
}

// ---------------------------------------------------------------------------
// Per-t batched GEMM: C[b-rows, t, n0+*] = sum_k A * Wsel
// 2-phase pipeline (T3): dbuf As via global_load_lds (pre-swizzled source),
// dbuf Ws reg-staged fp32->bf16 cvt_pk, ONE barrier per K-tile, STAGE(next)
// before compute(cur). 8 waves, BN=128, BK=32.
// MI=2: BM=256 (logmx=0)  [bitwise = round-8/9/10 PASS codegen]
// MI=1: BM=128, mx m-blocks (round 12: O-proj/down 256->512 blocks = 2/CU,
//        halves per-block serial barrier-drain depth; same k-order => same bits)
// 1-D grid, XCD same-t grouping (j mod 8 == t mod 8 for all m,n blocks).
// ---------------------------------------------------------------------------
template<bool OUT_BF16, int MI>
__global__ __launch_bounds__(512, 4)
void gemm_tk(const unsigned short* __restrict__ A, const float* __restrict__ W0,
             const float* __restrict__ W1, void* __restrict__ C,
             int Ka, int N, int lognx, int logmx, int ldC)
{
  const int j = blockIdx.x;
  const int t = (j & 7) + 8 * (j >> (3 + lognx + logmx));
  const int nblk = (j >> 3) & ((1 << lognx) - 1);
  const int mblk = (j >> (3 + lognx)) & ((1 << logmx) - 1);
  const int n0blk = nblk * 128;
  const float* Wsel = (n0blk >= N) ? W1 : W0;
  const int n0w = (n0blk >= N) ? (n0blk - N) : n0blk;

  const int tid = threadIdx.x;
  const int lane = tid & 63;
  const int wv = tid >> 6;          // 0..7
  const int wrow = wv * (MI * 16);  // MI=2: 32 rows/wave; MI=1: 16

  __shared__ short As[2][MI * 128 * 32];  // [m][k] 64-B rows, swz32
  __shared__ short Ws[2][128 * 32];       // [n][k] 64-B rows, swz32; 2 x 8KB

  f32x4 acc[MI][8];
#pragma unroll
  for (int i = 0; i < MI; ++i)
#pragma unroll
    for (int jj = 0; jj < 8; ++jj) acc[i][jj] = f32x4{0.f, 0.f, 0.f, 0.f};

  const long ldA = 128L * Ka;
  const unsigned short* Ab = A + (long)t * Ka + (long)mblk * 128 * ldA;
  const float* Wb = Wsel + (long)t * Ka * N + n0w;

  const int n0 = (tid & 31) * 4;  // 4 consecutive n per thread (W staging)
  const int kp = tid >> 5;        // k-pair 0..15 (W staging)

  // ---- prologue: stage tile 0 into As[0]/Ws[0]
#pragma unroll
  for (int it = 0; it < MI; ++it) {
    int ci = tid + it * 512;            // 16B chunk id; m=ci>>2
    int m = ci >> 2, cb = (ci & 3) * 16;
    gload16((const char*)(Ab + (long)m * ldA) + (cb ^ swz32(m)),
            (char*)(&As[0][0]) + ci * 16);
  }
  {
    f32x4 wlo = *(const f32x4*)(Wb + (long)(kp * 2) * N + n0);
    f32x4 whi = *(const f32x4*)(Wb + (long)(kp * 2 + 1) * N + n0);
#pragma unroll
    for (int jj = 0; jj < 4; ++jj) {
      int n = n0 + jj;
      *(unsigned*)((char*)(&Ws[0][0]) + n * 64 + ((kp * 4) ^ swz32(n))) =
          cvt_pk_bf16(wlo[jj], whi[jj]);
    }
  }

  const int nt = Ka >> 5;
  int cur = 0;
  for (int kt = 0; kt < nt; ++kt) {
    __syncthreads();  // drain: As[cur]/Ws[cur] ready, prior reads of other buf done
    const bool more = (kt + 1) < nt;
    f32x4 wlo, whi;
    if (more) {
      // STAGE(next) first: loads fly during compute, drained at next barrier
      const unsigned short* An = Ab + (kt + 1) * 32;
#pragma unroll
      for (int it = 0; it < MI; ++it) {
        int ci = tid + it * 512;
        int m = ci >> 2, cb = (ci & 3) * 16;
        gload16((const char*)(An + (long)m * ldA) + (cb ^ swz32(m)),
                (char*)(&As[cur ^ 1][0]) + ci * 16);
      }
      const float* Wn = Wb + (long)(kt + 1) * 32 * N;
      wlo = *(const f32x4*)(Wn + (long)(kp * 2) * N + n0);
      whi = *(const f32x4*)(Wn + (long)(kp * 2 + 1) * N + n0);
    }
    // ---- compute tile kt
    const int kb2 = (lane >> 4) * 16;  // k-chunk byte offset
    bf8 a[MI];
#pragma unroll
    for (int mi = 0; mi < MI; ++mi) {
      const int m0 = wrow + mi * 16 + (lane & 15);
      a[mi] = *(const bf8*)((const char*)(&As[cur][0]) + m0 * 64 + (kb2 ^ swz32(m0)));
    }
#pragma unroll
    for (int ni = 0; ni < 8; ++ni) {
      const int n = ni * 16 + (lane & 15);
      bf8 bfr = *(const bf8*)((const char*)(&Ws[cur][0]) + n * 64 + (kb2 ^ swz32(n)));
#pragma unroll
      for (int mi = 0; mi < MI; ++mi)
        acc[mi][ni] = __builtin_amdgcn_mfma_f32_16x16x32_bf16(a[mi], bfr, acc[mi][ni], 0, 0, 0);
    }
    if (more) {
#pragma unroll
      for (int jj = 0; jj < 4; ++jj) {
        int n = n0 + jj;
        *(unsigned*)((char*)(&Ws[cur ^ 1][0]) + n * 64 + ((kp * 4) ^ swz32(n))) =
            cvt_pk_bf16(wlo[jj], whi[jj]);
      }
    }
    cur ^= 1;
  }
  // epilogue: C/D layout col=lane&15, row=(lane>>4)*4+reg
#pragma unroll
  for (int mi = 0; mi < MI; ++mi)
#pragma unroll
    for (int ni = 0; ni < 8; ++ni)
#pragma unroll
      for (int r = 0; r < 4; ++r) {
        int m = mblk * 128 + wrow + mi * 16 + (lane >> 4) * 4 + r;
        int n = n0blk + ni * 16 + (lane & 15);
        long off = ((long)m * 128 + t) * ldC + n;
        float v = acc[mi][ni][r];
        if constexpr (OUT_BF16) reinterpret_cast<unsigned short*>(C)[off] = f2bf(v);
        else reinterpret_cast<float*>(C)[off] = v;
      }
}

// ---------------------------------------------------------------------------
// fp32 -> bf16 convert (X)
// ---------------------------------------------------------------------------
__global__ __launch_bounds__(256)
void cvt_bf(const float* __restrict__ in, unsigned short* __restrict__ out, long n)
{
  long i = ((long)blockIdx.x * 256 + threadIdx.x) * 8;
  if (i >= n) return;
  f32x4 a = *reinterpret_cast<const f32x4*>(in + i);
  f32x4 b = *reinterpret_cast<const f32x4*>(in + i + 4);
  u16x4 w0, w1;
#pragma unroll
  for (int j = 0; j < 4; ++j) { w0[j] = f2bf(a[j]); w1[j] = f2bf(b[j]); }
  *reinterpret_cast<u16x4*>(out + i) = w0;
  *reinterpret_cast<u16x4*>(out + i + 4) = w1;
}

// ---------------------------------------------------------------------------
// v (B,T,H*256) -> vT (B*H, 256, 128)   [known-good]
// ---------------------------------------------------------------------------
__global__ __launch_bounds__(256)
void trans_v(const unsigned short* __restrict__ vb, unsigned short* __restrict__ vT)
{
  const int bh = blockIdx.y;
  const int b = bh >> 3, h = bh & 7;
  const int tile = blockIdx.x;   // 0..31
  const int tt = tile >> 3;      // t-tile (4)
  const int td = tile & 7;       // d-tile (8)
  __shared__ unsigned short sm[32][33];
  const int rloc = threadIdx.x >> 3;
  const int q4 = (threadIdx.x & 7) * 4;
  {
    long off = ((long)b * 128 + tt * 32 + rloc) * 2048 + h * 256 + td * 32 + q4;
    u16x4 v = *reinterpret_cast<const u16x4*>(vb + off);
#pragma unroll
    for (int j = 0; j < 4; ++j) sm[rloc][q4 + j] = v[j];
  }
  __syncthreads();
  {
    u16x4 w;
#pragma unroll
    for (int j = 0; j < 4; ++j) w[j] = sm[q4 + j][rloc];
    long off = ((long)bh * 256 + td * 32 + rloc) * 128 + tt * 32 + q4;
    *reinterpret_cast<u16x4*>(vT + off) = w;
  }
}

// ---------------------------------------------------------------------------
// Fused attention for one (b,h). [reverted to round-10 PASS version verbatim:
// 512 thr / 8 waves / 16 t-rows per wave; ps LDS; round-11 shfl port REGRESSED]
// ---------------------------------------------------------------------------
__global__ __launch_bounds__(512, 4)
void attn_k(const unsigned short* __restrict__ qk, const unsigned short* __restrict__ vT,
            unsigned short* __restrict__ cat)
{
  const int h = blockIdx.x, b = blockIdx.y;
  const int tid = threadIdx.x, lane = tid & 63, wv = tid >> 6;
  const int wrow = wv * 16;          // 16 rows per wave

  __shared__ short ps[128 * 128];    // P [t][s] swizzled (256-B rows), 32KB
  __shared__ short vs[2][256 * 32];  // vT s-chunk [d][s32] 64-B rows swz32, 2x16KB

  const long qkBase = ((long)b * 128) * 512 + h * 32;
  const long vBase = ((long)(b * 8 + h)) * 256 * 128;
  const int kb_ = (lane >> 4) * 8;

  // stage s-chunk 0 into vs[0] (issue-only; drained at first barrier).
#pragma unroll
  for (int it = 0; it < 2; ++it) {
    int ci = tid + it * 512;
    int d = ci >> 2, sc = ci & 3;
    gload16(vT + vBase + (long)d * 128 + (((sc * 16) ^ swz32(d)) >> 1),
            (char*)(&vs[0][0]) + ci * 16);
  }

  // S = q k^T  (q/k frags straight from global; AE=32 = one MFMA K-step)
  f32x4 sacc[8];
#pragma unroll
  for (int c = 0; c < 8; ++c) sacc[c] = f32x4{0.f, 0.f, 0.f, 0.f};
  bf8 aq;
  {
    int row = wrow + (lane & 15);
    aq = *reinterpret_cast<const bf8*>(qk + qkBase + (long)row * 512 + kb_);
  }
#pragma unroll
  for (int ni = 0; ni < 8; ++ni) {
    int s = ni * 16 + (lane & 15);
    bf8 bk = *reinterpret_cast<const bf8*>(qk + qkBase + 256 + (long)s * 512 + kb_);
    sacc[ni] = __builtin_amdgcn_mfma_f32_16x16x32_bf16(aq, bk, sacc[ni], 0, 0, 0);
  }

  // wave-parallel softmax; P written unnormalized (divide after PV)
  const float scale = 0.17677669529663687f;  // 1/sqrt(32)
  float sinv[4];
#pragma unroll
  for (int r = 0; r < 4; ++r) {
    int row = wrow + (lane >> 4) * 4 + r;
    float vv[8];
    float mx = -1e30f;
#pragma unroll
    for (int c = 0; c < 8; ++c) { vv[c] = sacc[c][r] * scale; mx = fmaxf(mx, vv[c]); }
#pragma unroll
    for (int mm = 1; mm < 16; mm <<= 1) mx = fmaxf(mx, __shfl_xor(mx, mm, 64));
    float s_ = 0.f;
#pragma unroll
    for (int c = 0; c < 8; ++c) { vv[c] = __expf(vv[c] - mx); s_ += vv[c]; }
#pragma unroll
    for (int mm = 1; mm < 16; mm <<= 1) s_ += __shfl_xor(s_, mm, 64);
    sinv[r] = 1.0f / s_;
#pragma unroll
    for (int c = 0; c < 8; ++c) {
      int col = c * 16 + (lane & 15);
      int byte = row * 256 + ((col * 2) ^ swz(row));
      *reinterpret_cast<unsigned short*>(reinterpret_cast<char*>(ps) + byte) = f2bf(vv[c]);
    }
  }

  // PV over four 32-wide s-chunks, double-buffered LDS (T3 2-phase).
  f32x4 oacc[16];
#pragma unroll
  for (int c = 0; c < 16; ++c) oacc[c] = f32x4{0.f, 0.f, 0.f, 0.f};

#pragma unroll 1
  for (int cs = 0; cs < 4; ++cs) {
    __syncthreads();  // vs[cs&1] staged (vmcnt drained); cs-1 compute done
    if (cs < 3) {
      // STAGE next chunk into the other buffer; overlaps this chunk's MFMAs
#pragma unroll
      for (int it = 0; it < 2; ++it) {
        int ci = tid + it * 512;
        int d = ci >> 2, sc = ci & 3;
        gload16(vT + vBase + (long)d * 128 + (cs + 1) * 32 + (((sc * 16) ^ swz32(d)) >> 1),
                (char*)(&vs[(cs + 1) & 1][0]) + ci * 16);
      }
    }
    const int kglob = cs * 32 + kb_;
    bf8 ap;
    {
      int row = wrow + (lane & 15);
      int byte = row * 256 + ((kglob * 2) ^ swz(row));
      ap = *reinterpret_cast<const bf8*>(reinterpret_cast<const char*>(ps) + byte);
    }
    __builtin_amdgcn_s_setprio(1);
#pragma unroll
    for (int c = 0; c < 16; ++c) {
      int d = c * 16 + (lane & 15);
      bf8 bv = *reinterpret_cast<const bf8*>(
          reinterpret_cast<const char*>(&vs[cs & 1][0]) + d * 64 + ((kb_ * 2) ^ swz32(d)));
      oacc[c] = __builtin_amdgcn_mfma_f32_16x16x32_bf16(ap, bv, oacc[c], 0, 0, 0);
    }
    __builtin_amdgcn_s_setprio(0);
  }

  // write cat[b,t,h*256+d] = out/row_sum (bf16)
#pragma unroll
  for (int c = 0; c < 16; ++c)
#pragma unroll
    for (int r = 0; r < 4; ++r) {
      int tt = wrow + (lane >> 4) * 4 + r;
      int d = c * 16 + (lane & 15);
      float v = oacc[c][r] * sinv[r];
      long off = ((long)b * 128 + tt) * 2048 + h * 256 + d;
      cat[off] = f2bf(v);
    }
}

// ---------------------------------------------------------------------------
// LayerNorm(a+b): a,b read as bf16; write fp32 (WF) and/or bf16 (WB).
// ---------------------------------------------------------------------------
template<bool WF, bool WB>
__global__ __launch_bounds__(256)
void ln_k(const unsigned short* __restrict__ a, const unsigned short* __restrict__ bsrc,
          const float* __restrict__ gamma, const float* __restrict__ beta,
          float* __restrict__ of, unsigned short* __restrict__ ob)
{
  const int row = blockIdx.x * 4 + (threadIdx.x >> 6);
  const int lane = threadIdx.x & 63;
  const long base = (long)row * 256 + lane * 4;
  u16x4 ua = *reinterpret_cast<const u16x4*>(a + base);
  u16x4 ub = *reinterpret_cast<const u16x4*>(bsrc + base);
  f32x4 x;
#pragma unroll
  for (int j = 0; j < 4; ++j) x[j] = bf2f(ua[j]) + bf2f(ub[j]);
  float s = x[0] + x[1] + x[2] + x[3];
  float s2 = x[0] * x[0] + x[1] * x[1] + x[2] * x[2] + x[3] * x[3];
#pragma unroll
  for (int mm = 1; mm < 64; mm <<= 1) { s += __shfl_xor(s, mm, 64); s2 += __shfl_xor(s2, mm, 64); }
  float mean = s * (1.f / 256.f);
  float var = fmaxf(s2 * (1.f / 256.f) - mean * mean, 0.f);
  float inv = rsqrtf(var + 1e-5f);
  f32x4 g = *reinterpret_cast<const f32x4*>(gamma + lane * 4);
  f32x4 be = *reinterpret_cast<const f32x4*>(beta + lane * 4);
  f32x4 y;
#pragma unroll
  for (int j = 0; j < 4; ++j) y[j] = (x[j] - mean) * inv * g[j] + be[j];
  if constexpr (WF) *reinterpret_cast<f32x4*>(of + base) = y;
  if constexpr (WB) {
    u16x4 w;
#pragma unroll
    for (int j = 0; j < 4; ++j) w[j] = f2bf(y[j]);
    *reinterpret_cast<u16x4*>(ob + base) = w;
  }
}

// ---------------------------------------------------------------------------
// hidden = silu(gate) * up, reading the fused gateup buffer.
// ---------------------------------------------------------------------------
__global__ __launch_bounds__(256)
void silu_k(const unsigned short* __restrict__ gu, unsigned short* __restrict__ o, long n)
{
  long i = ((long)blockIdx.x * 256 + threadIdx.x) * 8;
  if (i >= n) return;
  long r = i >> 9;
  int f = (int)(i & 511);
  const unsigned short* g = gu + r * 1024 + f;
  const unsigned short* u = g + 512;
  u16x4 g0 = *reinterpret_cast<const u16x4*>(g);
  u16x4 g1 = *reinterpret_cast<const u16x4*>(g + 4);
  u16x4 u0 = *reinterpret_cast<const u16x4*>(u);
  u16x4 u1 = *reinterpret_cast<const u16x4*>(u + 4);
  u16x4 o0, o1;
#pragma unroll
  for (int j = 0; j < 4; ++j) {
    float gg = bf2f(g0[j]), uu = bf2f(u0[j]);
    o0[j] = f2bf(gg / (1.f + __expf(-gg)) * uu);
    gg = bf2f(g1[j]); uu = bf2f(u1[j]);
    o1[j] = f2bf(gg / (1.f + __expf(-gg)) * uu);
  }
  *reinterpret_cast<u16x4*>(o + i) = o0;
  *reinterpret_cast<u16x4*>(o + i + 4) = o1;
}

// ---------------------------------------------------------------------------
// Workspace (304 MiB, lifetime reuse). All LN-chain intermediates bf16:
//   [0,16) Xb   [16,48) qkb
//   regA @48MiB (128): vb(128) -> cat(128) -> gateup(64)|hid@64(32)
//   regB @176MiB (128): vT(128) -> attnpb@0(16)|x1b@16(16)|ffnb@32(16)
// ---------------------------------------------------------------------------
extern "C" void kernel_launch(void* const* d_in, const int* in_sizes, int n_in,
                              void* d_out, int out_size, void* d_ws, size_t ws_size,
                              hipStream_t stream)
{
  const float* X  = (const float*)d_in[0];
  const float* Qw = (const float*)d_in[1];
  const float* Kw = (const float*)d_in[2];
  const float* Vw = (const float*)d_in[3];
  const float* Ow = (const float*)d_in[4];
  const float* Wg = (const float*)d_in[5];
  const float* Wu = (const float*)d_in[6];
  const float* Wd = (const float*)d_in[7];
  const float* g1 = (const float*)d_in[8];
  const float* b1 = (const float*)d_in[9];
  const float* g2 = (const float*)d_in[10];
  const float* b2 = (const float*)d_in[11];

  char* ws = (char*)d_ws;
  const size_t MiB = 1048576;
  unsigned short* Xb  = (unsigned short*)(ws);
  unsigned short* qkb = (unsigned short*)(ws + 16 * MiB);
  char* regA = ws + 48 * MiB;    // 128 MiB
  char* regB = regA + 128 * MiB; // 128 MiB

  unsigned short* vb     = (unsigned short*)regA;           // dead after trans_v
  unsigned short* vT     = (unsigned short*)regB;           // dead after attn_k
  unsigned short* cat    = (unsigned short*)regA;           // attn out (vb dead)
  unsigned short* attnpb = (unsigned short*)(regB);         // O-proj out bf16 (vT dead)
  unsigned short* x1b    = (unsigned short*)(regB + 16 * MiB);
  unsigned short* ffnb   = (unsigned short*)(regB + 32 * MiB);
  unsigned short* gateup = (unsigned short*)(regA);         // cat dead after O-proj
  unsigned short* hidb   = (unsigned short*)(regA + 64 * MiB);
  float* out = (float*)d_out;

  dim3 blk(256), gblk(512);
  cvt_bf<<<dim3(4096), blk, 0, stream>>>(X, Xb, (long)8388608);
  // Q|K fused: N=256 each, ldC=512, nx=4 -> 512 blocks (MI=2)
  gemm_tk<true, 2><<<dim3(512), gblk, 0, stream>>>(Xb, Qw, Kw, (void*)qkb, 256, 256, 2, 0, 512);
  // V: nx=16 -> 2048 blocks (MI=2)
  gemm_tk<true, 2><<<dim3(2048), gblk, 0, stream>>>(Xb, Vw, Vw, (void*)vb, 256, 2048, 4, 0, 2048);
  trans_v<<<dim3(32, 2048), blk, 0, stream>>>(vb, vT);
  attn_k<<<dim3(8, 256), gblk, 0, stream>>>(qkb, vT, cat);
  // O-proj -> bf16: MI=1 M-split (nx=2, mx=2) -> 512 blocks = 2/CU
  gemm_tk<true, 1><<<dim3(512), gblk, 0, stream>>>(cat, Ow, Ow, (void*)attnpb, 2048, 256, 1, 1, 256);
  // ln1: x1 = LN(Xb + attnpb) -> x1b only
  ln_k<false, true><<<dim3(8192), blk, 0, stream>>>(Xb, attnpb, g1, b1, (float*)nullptr, x1b);
  // gate|up fused: N=512 each, ldC=1024, nx=8 -> 1024 blocks (MI=2)
  gemm_tk<true, 2><<<dim3(1024), gblk, 0, stream>>>(x1b, Wg, Wu, (void*)gateup, 256, 512, 3, 0, 1024);
  silu_k<<<dim3(8192), blk, 0, stream>>>(gateup, hidb, (long)16777216);
  // down -> bf16: MI=1 M-split (nx=2, mx=2) -> 512 blocks = 2/CU
  gemm_tk<true, 1><<<dim3(512), gblk, 0, stream>>>(hidb, Wd, Wd, (void*)ffnb, 512, 256, 1, 1, 256);
  // ln2: out = LN(x1b + ffnb) -> fp32 d_out
  ln_k<true, false><<<dim3(8192), blk, 0, stream>>>(x1b, ffnb, g2, b2, out, (unsigned short*)nullptr);
}

// Round 13
// 465.121 us; speedup vs baseline: 1.2118x; 1.1507x over previous
//
#include <hip/hip_runtime.h>
#include <stdint.h>

// Problem constants: B=256, T=128, D=256, H=8, AE=32, DFF=512
#define DEVI static __device__ __forceinline__

typedef __attribute__((ext_vector_type(4))) float f32x4;
typedef __attribute__((ext_vector_type(8))) short bf8;     // 8 bf16 (MFMA A/B frag)
typedef __attribute__((ext_vector_type(4))) unsigned short u16x4;

DEVI unsigned short f2bf(float f) {
  unsigned u = __builtin_bit_cast(unsigned, f);
  u = (u + 0x7FFFu + ((u >> 16) & 1u)) >> 16;
  return (unsigned short)u;
}
DEVI float bf2f(unsigned short s) {
  return __builtin_bit_cast(float, ((unsigned)s) << 16);
}
DEVI unsigned cvt_pk_bf16(float lo, float hi) {
  unsigned r;
  asm("v_cvt_pk_bf16_f32 %0, %1, %2" : "=v"(r) : "v"(lo), "v"(hi));
  return r;
}
// swizzle for 256-B rows (attn ps): 16B granularity, 8 slots
DEVI int swz(int row) { return (((row >> 2) ^ row) & 7) << 4; }
// swizzle for 64-B rows (gemm As/Ws, attn vs): 16B granularity, 4 slots
DEVI int swz32(int row) { return (((row >> 1) ^ row) & 3) << 4; }

DEVI void gload16(const void* g, void* l) {
  __builtin_amdgcn_global_load_lds(
      (const __attribute__((address_space(1))) unsigned*)g,
      (__attribute__((address_space(3))) unsigned*)l, 16, 0, 0);
}

// ---------------------------------------------------------------------------
// Per-t batched GEMM: C[b-rows, t, n0+*] = sum_k A * Wsel
// 2-phase pipeline (T3): dbuf As via global_load_lds (pre-swizzled source),
// dbuf Ws reg-staged fp32->bf16 cvt_pk, ONE barrier per K-tile, STAGE(next)
// before compute(cur). 8 waves, BN=128, BK=32.
// MI=2: BM=256; MI=1: BM=128 with mx m-blocks (O-proj/down: 2 blocks/CU).
// 1-D grid, XCD same-t grouping + two-weight fusion. [= round-12 PASS]
// ---------------------------------------------------------------------------
template<bool OUT_BF16, int MI>
__global__ __launch_bounds__(512, 4)
void gemm_tk(const unsigned short* __restrict__ A, const float* __restrict__ W0,
             const float* __restrict__ W1, void* __restrict__ C,
             int Ka, int N, int lognx, int logmx, int ldC)
{
  const int j = blockIdx.x;
  const int t = (j & 7) + 8 * (j >> (3 + lognx + logmx));
  const int nblk = (j >> 3) & ((1 << lognx) - 1);
  const int mblk = (j >> (3 + lognx)) & ((1 << logmx) - 1);
  const int n0blk = nblk * 128;
  const float* Wsel = (n0blk >= N) ? W1 : W0;
  const int n0w = (n0blk >= N) ? (n0blk - N) : n0blk;

  const int tid = threadIdx.x;
  const int lane = tid & 63;
  const int wv = tid >> 6;          // 0..7
  const int wrow = wv * (MI * 16);  // MI=2: 32 rows/wave; MI=1: 16

  __shared__ short As[2][MI * 128 * 32];  // [m][k] 64-B rows, swz32
  __shared__ short Ws[2][128 * 32];       // [n][k] 64-B rows, swz32; 2 x 8KB

  f32x4 acc[MI][8];
#pragma unroll
  for (int i = 0; i < MI; ++i)
#pragma unroll
    for (int jj = 0; jj < 8; ++jj) acc[i][jj] = f32x4{0.f, 0.f, 0.f, 0.f};

  const long ldA = 128L * Ka;
  const unsigned short* Ab = A + (long)t * Ka + (long)mblk * 128 * ldA;
  const float* Wb = Wsel + (long)t * Ka * N + n0w;

  const int n0 = (tid & 31) * 4;  // 4 consecutive n per thread (W staging)
  const int kp = tid >> 5;        // k-pair 0..15 (W staging)

  // ---- prologue: stage tile 0 into As[0]/Ws[0]
#pragma unroll
  for (int it = 0; it < MI; ++it) {
    int ci = tid + it * 512;            // 16B chunk id; m=ci>>2
    int m = ci >> 2, cb = (ci & 3) * 16;
    gload16((const char*)(Ab + (long)m * ldA) + (cb ^ swz32(m)),
            (char*)(&As[0][0]) + ci * 16);
  }
  {
    f32x4 wlo = *(const f32x4*)(Wb + (long)(kp * 2) * N + n0);
    f32x4 whi = *(const f32x4*)(Wb + (long)(kp * 2 + 1) * N + n0);
#pragma unroll
    for (int jj = 0; jj < 4; ++jj) {
      int n = n0 + jj;
      *(unsigned*)((char*)(&Ws[0][0]) + n * 64 + ((kp * 4) ^ swz32(n))) =
          cvt_pk_bf16(wlo[jj], whi[jj]);
    }
  }

  const int nt = Ka >> 5;
  int cur = 0;
  for (int kt = 0; kt < nt; ++kt) {
    __syncthreads();  // drain: As[cur]/Ws[cur] ready, prior reads of other buf done
    const bool more = (kt + 1) < nt;
    f32x4 wlo, whi;
    if (more) {
      // STAGE(next) first: loads fly during compute, drained at next barrier
      const unsigned short* An = Ab + (kt + 1) * 32;
#pragma unroll
      for (int it = 0; it < MI; ++it) {
        int ci = tid + it * 512;
        int m = ci >> 2, cb = (ci & 3) * 16;
        gload16((const char*)(An + (long)m * ldA) + (cb ^ swz32(m)),
                (char*)(&As[cur ^ 1][0]) + ci * 16);
      }
      const float* Wn = Wb + (long)(kt + 1) * 32 * N;
      wlo = *(const f32x4*)(Wn + (long)(kp * 2) * N + n0);
      whi = *(const f32x4*)(Wn + (long)(kp * 2 + 1) * N + n0);
    }
    // ---- compute tile kt
    const int kb2 = (lane >> 4) * 16;  // k-chunk byte offset
    bf8 a[MI];
#pragma unroll
    for (int mi = 0; mi < MI; ++mi) {
      const int m0 = wrow + mi * 16 + (lane & 15);
      a[mi] = *(const bf8*)((const char*)(&As[cur][0]) + m0 * 64 + (kb2 ^ swz32(m0)));
    }
#pragma unroll
    for (int ni = 0; ni < 8; ++ni) {
      const int n = ni * 16 + (lane & 15);
      bf8 bfr = *(const bf8*)((const char*)(&Ws[cur][0]) + n * 64 + (kb2 ^ swz32(n)));
#pragma unroll
      for (int mi = 0; mi < MI; ++mi)
        acc[mi][ni] = __builtin_amdgcn_mfma_f32_16x16x32_bf16(a[mi], bfr, acc[mi][ni], 0, 0, 0);
    }
    if (more) {
#pragma unroll
      for (int jj = 0; jj < 4; ++jj) {
        int n = n0 + jj;
        *(unsigned*)((char*)(&Ws[cur ^ 1][0]) + n * 64 + ((kp * 4) ^ swz32(n))) =
            cvt_pk_bf16(wlo[jj], whi[jj]);
      }
    }
    cur ^= 1;
  }
  // epilogue: C/D layout col=lane&15, row=(lane>>4)*4+reg
#pragma unroll
  for (int mi = 0; mi < MI; ++mi)
#pragma unroll
    for (int ni = 0; ni < 8; ++ni)
#pragma unroll
      for (int r = 0; r < 4; ++r) {
        int m = mblk * 128 + wrow + mi * 16 + (lane >> 4) * 4 + r;
        int n = n0blk + ni * 16 + (lane & 15);
        long off = ((long)m * 128 + t) * ldC + n;
        float v = acc[mi][ni][r];
        if constexpr (OUT_BF16) reinterpret_cast<unsigned short*>(C)[off] = f2bf(v);
        else reinterpret_cast<float*>(C)[off] = v;
      }
}

// ---------------------------------------------------------------------------
// fp32 -> bf16 convert (X)
// ---------------------------------------------------------------------------
__global__ __launch_bounds__(256)
void cvt_bf(const float* __restrict__ in, unsigned short* __restrict__ out, long n)
{
  long i = ((long)blockIdx.x * 256 + threadIdx.x) * 8;
  if (i >= n) return;
  f32x4 a = *reinterpret_cast<const f32x4*>(in + i);
  f32x4 b = *reinterpret_cast<const f32x4*>(in + i + 4);
  u16x4 w0, w1;
#pragma unroll
  for (int j = 0; j < 4; ++j) { w0[j] = f2bf(a[j]); w1[j] = f2bf(b[j]); }
  *reinterpret_cast<u16x4*>(out + i) = w0;
  *reinterpret_cast<u16x4*>(out + i + 4) = w1;
}

// ---------------------------------------------------------------------------
// attn staging helper: write one thread's transposed V chunk into vs.
// Thread holds V[s=2*s2][d0..d0+7] (r0) and V[2*s2+1][d0..d0+7] (r1).
// LDS image target (= what the proven PV b128 read expects):
//   element (d, s) at byte d*64 + ((2*s) ^ swz32(d)).
// b32 at byte d*64 + ((4*s2)^swz32(d)) packs {s=2s2 (lo), s=2s2+1 (hi)}.
// Banks per write instr: 16(j&1) + (s2^const) -> 16 banks/64 lanes = 4-way.
// ---------------------------------------------------------------------------
DEVI void stage_write_v(short* buf, f32x4 r0, f32x4 r1, int s2, int d0)
{
  const unsigned* a = reinterpret_cast<const unsigned*>(&r0);  // 4 words, 2 bf16 each
  const unsigned* c = reinterpret_cast<const unsigned*>(&r1);
#pragma unroll
  for (int j = 0; j < 8; ++j) {
    unsigned lo = (j & 1) ? (a[j >> 1] >> 16) : (a[j >> 1] & 0xFFFFu);
    unsigned hi = (j & 1) ? (c[j >> 1] >> 16) : (c[j >> 1] & 0xFFFFu);
    int d = d0 + j;
    *reinterpret_cast<unsigned*>(reinterpret_cast<char*>(buf) + d * 64 + ((4 * s2) ^ swz32(d))) =
        lo | (hi << 16);
  }
}

// ---------------------------------------------------------------------------
// Fused attention for one (b,h). Round 13: V read DIRECTLY from vb
// (b,s,2048) — trans_v eliminated. Staging = reg-staged transpose (T14):
// loads issued after the barrier, ds_write_b32 after the MFMA cluster.
// LDS image, PV reads, k-order, softmax: identical to round-12 PASS
// => bitwise-identical output.
// ---------------------------------------------------------------------------
__global__ __launch_bounds__(512, 4)
void attn_k(const unsigned short* __restrict__ qk, const unsigned short* __restrict__ vg,
            unsigned short* __restrict__ cat)
{
  const int h = blockIdx.x, b = blockIdx.y;
  const int tid = threadIdx.x, lane = tid & 63, wv = tid >> 6;
  const int wrow = wv * 16;          // 16 rows per wave

  __shared__ short ps[128 * 128];    // P [t][s] swizzled (256-B rows), 32KB
  __shared__ short vs[2][256 * 32];  // V chunk [d][s32] 64-B rows swz32, 2x16KB

  const long qkBase = ((long)b * 128) * 512 + h * 32;
  const long vgBase = ((long)b * 128) * 2048 + h * 256;  // + s*2048 + d
  const int kb_ = (lane >> 4) * 8;

  // transpose-staging mapping: s-pair + 8-d group per thread
  const int s2 = tid & 15;        // s = 2*s2, 2*s2+1
  const int d0 = (tid >> 4) * 8;  // 0..248

  // ---- issue chunk-0 loads (consumed after softmax, before first barrier)
  f32x4 r0, r1;
  {
    const unsigned short* src = vg + vgBase + (long)(2 * s2) * 2048 + d0;
    r0 = *reinterpret_cast<const f32x4*>(src);
    r1 = *reinterpret_cast<const f32x4*>(src + 2048);
  }

  // S = q k^T  (q/k frags straight from global; AE=32 = one MFMA K-step)
  f32x4 sacc[8];
#pragma unroll
  for (int c = 0; c < 8; ++c) sacc[c] = f32x4{0.f, 0.f, 0.f, 0.f};
  bf8 aq;
  {
    int row = wrow + (lane & 15);
    aq = *reinterpret_cast<const bf8*>(qk + qkBase + (long)row * 512 + kb_);
  }
#pragma unroll
  for (int ni = 0; ni < 8; ++ni) {
    int s = ni * 16 + (lane & 15);
    bf8 bk = *reinterpret_cast<const bf8*>(qk + qkBase + 256 + (long)s * 512 + kb_);
    sacc[ni] = __builtin_amdgcn_mfma_f32_16x16x32_bf16(aq, bk, sacc[ni], 0, 0, 0);
  }

  // wave-parallel softmax; P written unnormalized (divide after PV)
  const float scale = 0.17677669529663687f;  // 1/sqrt(32)
  float sinv[4];
#pragma unroll
  for (int r = 0; r < 4; ++r) {
    int row = wrow + (lane >> 4) * 4 + r;
    float vv[8];
    float mx = -1e30f;
#pragma unroll
    for (int c = 0; c < 8; ++c) { vv[c] = sacc[c][r] * scale; mx = fmaxf(mx, vv[c]); }
#pragma unroll
    for (int mm = 1; mm < 16; mm <<= 1) mx = fmaxf(mx, __shfl_xor(mx, mm, 64));
    float s_ = 0.f;
#pragma unroll
    for (int c = 0; c < 8; ++c) { vv[c] = __expf(vv[c] - mx); s_ += vv[c]; }
#pragma unroll
    for (int mm = 1; mm < 16; mm <<= 1) s_ += __shfl_xor(s_, mm, 64);
    sinv[r] = 1.0f / s_;
#pragma unroll
    for (int c = 0; c < 8; ++c) {
      int col = c * 16 + (lane & 15);
      int byte = row * 256 + ((col * 2) ^ swz(row));
      *reinterpret_cast<unsigned short*>(reinterpret_cast<char*>(ps) + byte) = f2bf(vv[c]);
    }
  }

  // write chunk 0 into vs[0] (loads had QK^T + softmax to land)
  stage_write_v(&vs[0][0], r0, r1, s2, d0);

  // PV over four 32-wide s-chunks, double-buffered LDS (T3 2-phase + T14).
  f32x4 oacc[16];
#pragma unroll
  for (int c = 0; c < 16; ++c) oacc[c] = f32x4{0.f, 0.f, 0.f, 0.f};

#pragma unroll 1
  for (int cs = 0; cs < 4; ++cs) {
    __syncthreads();  // vs[cs&1] published; all waves done reading vs[(cs+1)&1]
    if (cs < 3) {
      // issue next-chunk loads now; consumed after this chunk's MFMAs
      const unsigned short* src = vg + vgBase + (long)((cs + 1) * 32 + 2 * s2) * 2048 + d0;
      r0 = *reinterpret_cast<const f32x4*>(src);
      r1 = *reinterpret_cast<const f32x4*>(src + 2048);
    }
    const int kglob = cs * 32 + kb_;
    bf8 ap;
    {
      int row = wrow + (lane & 15);
      int byte = row * 256 + ((kglob * 2) ^ swz(row));
      ap = *reinterpret_cast<const bf8*>(reinterpret_cast<const char*>(ps) + byte);
    }
    __builtin_amdgcn_s_setprio(1);
#pragma unroll
    for (int c = 0; c < 16; ++c) {
      int d = c * 16 + (lane & 15);
      bf8 bv = *reinterpret_cast<const bf8*>(
          reinterpret_cast<const char*>(&vs[cs & 1][0]) + d * 64 + ((kb_ * 2) ^ swz32(d)));
      oacc[c] = __builtin_amdgcn_mfma_f32_16x16x32_bf16(ap, bv, oacc[c], 0, 0, 0);
    }
    __builtin_amdgcn_s_setprio(0);
    if (cs < 3) stage_write_v(&vs[(cs + 1) & 1][0], r0, r1, s2, d0);
  }

  // write cat[b,t,h*256+d] = out/row_sum (bf16)
#pragma unroll
  for (int c = 0; c < 16; ++c)
#pragma unroll
    for (int r = 0; r < 4; ++r) {
      int tt = wrow + (lane >> 4) * 4 + r;
      int d = c * 16 + (lane & 15);
      float v = oacc[c][r] * sinv[r];
      long off = ((long)b * 128 + tt) * 2048 + h * 256 + d;
      cat[off] = f2bf(v);
    }
}

// ---------------------------------------------------------------------------
// LayerNorm(a+b): a,b read as bf16; write fp32 (WF) and/or bf16 (WB).
// ---------------------------------------------------------------------------
template<bool WF, bool WB>
__global__ __launch_bounds__(256)
void ln_k(const unsigned short* __restrict__ a, const unsigned short* __restrict__ bsrc,
          const float* __restrict__ gamma, const float* __restrict__ beta,
          float* __restrict__ of, unsigned short* __restrict__ ob)
{
  const int row = blockIdx.x * 4 + (threadIdx.x >> 6);
  const int lane = threadIdx.x & 63;
  const long base = (long)row * 256 + lane * 4;
  u16x4 ua = *reinterpret_cast<const u16x4*>(a + base);
  u16x4 ub = *reinterpret_cast<const u16x4*>(bsrc + base);
  f32x4 x;
#pragma unroll
  for (int j = 0; j < 4; ++j) x[j] = bf2f(ua[j]) + bf2f(ub[j]);
  float s = x[0] + x[1] + x[2] + x[3];
  float s2 = x[0] * x[0] + x[1] * x[1] + x[2] * x[2] + x[3] * x[3];
#pragma unroll
  for (int mm = 1; mm < 64; mm <<= 1) { s += __shfl_xor(s, mm, 64); s2 += __shfl_xor(s2, mm, 64); }
  float mean = s * (1.f / 256.f);
  float var = fmaxf(s2 * (1.f / 256.f) - mean * mean, 0.f);
  float inv = rsqrtf(var + 1e-5f);
  f32x4 g = *reinterpret_cast<const f32x4*>(gamma + lane * 4);
  f32x4 be = *reinterpret_cast<const f32x4*>(beta + lane * 4);
  f32x4 y;
#pragma unroll
  for (int j = 0; j < 4; ++j) y[j] = (x[j] - mean) * inv * g[j] + be[j];
  if constexpr (WF) *reinterpret_cast<f32x4*>(of + base) = y;
  if constexpr (WB) {
    u16x4 w;
#pragma unroll
    for (int j = 0; j < 4; ++j) w[j] = f2bf(y[j]);
    *reinterpret_cast<u16x4*>(ob + base) = w;
  }
}

// ---------------------------------------------------------------------------
// hidden = silu(gate) * up, reading the fused gateup buffer.
// ---------------------------------------------------------------------------
__global__ __launch_bounds__(256)
void silu_k(const unsigned short* __restrict__ gu, unsigned short* __restrict__ o, long n)
{
  long i = ((long)blockIdx.x * 256 + threadIdx.x) * 8;
  if (i >= n) return;
  long r = i >> 9;
  int f = (int)(i & 511);
  const unsigned short* g = gu + r * 1024 + f;
  const unsigned short* u = g + 512;
  u16x4 g0 = *reinterpret_cast<const u16x4*>(g);
  u16x4 g1 = *reinterpret_cast<const u16x4*>(g + 4);
  u16x4 u0 = *reinterpret_cast<const u16x4*>(u);
  u16x4 u1 = *reinterpret_cast<const u16x4*>(u + 4);
  u16x4 o0, o1;
#pragma unroll
  for (int j = 0; j < 4; ++j) {
    float gg = bf2f(g0[j]), uu = bf2f(u0[j]);
    o0[j] = f2bf(gg / (1.f + __expf(-gg)) * uu);
    gg = bf2f(g1[j]); uu = bf2f(u1[j]);
    o1[j] = f2bf(gg / (1.f + __expf(-gg)) * uu);
  }
  *reinterpret_cast<u16x4*>(o + i) = o0;
  *reinterpret_cast<u16x4*>(o + i + 4) = o1;
}

// ---------------------------------------------------------------------------
// Workspace (304 MiB, lifetime reuse; trans_v/vT ELIMINATED):
//   [0,16) Xb   [16,48) qkb
//   regA @48MiB (128): vb(128, dead after attn) -> attnpb@0(16)|x1b@16(16)|
//                      gateup@32(64, dead after silu)|hid@96(32)|ffnb@32(16)
//   regB @176MiB (128): cat(128, dead after O-proj)
// ---------------------------------------------------------------------------
extern "C" void kernel_launch(void* const* d_in, const int* in_sizes, int n_in,
                              void* d_out, int out_size, void* d_ws, size_t ws_size,
                              hipStream_t stream)
{
  const float* X  = (const float*)d_in[0];
  const float* Qw = (const float*)d_in[1];
  const float* Kw = (const float*)d_in[2];
  const float* Vw = (const float*)d_in[3];
  const float* Ow = (const float*)d_in[4];
  const float* Wg = (const float*)d_in[5];
  const float* Wu = (const float*)d_in[6];
  const float* Wd = (const float*)d_in[7];
  const float* g1 = (const float*)d_in[8];
  const float* b1 = (const float*)d_in[9];
  const float* g2 = (const float*)d_in[10];
  const float* b2 = (const float*)d_in[11];

  char* ws = (char*)d_ws;
  const size_t MiB = 1048576;
  unsigned short* Xb  = (unsigned short*)(ws);
  unsigned short* qkb = (unsigned short*)(ws + 16 * MiB);
  char* regA = ws + 48 * MiB;    // 128 MiB
  char* regB = regA + 128 * MiB; // 128 MiB

  unsigned short* vb     = (unsigned short*)regA;           // dead after attn_k
  unsigned short* cat    = (unsigned short*)regB;           // dead after O-proj
  unsigned short* attnpb = (unsigned short*)(regA);         // O-proj out (vb dead)
  unsigned short* x1b    = (unsigned short*)(regA + 16 * MiB);
  unsigned short* gateup = (unsigned short*)(regA + 32 * MiB);  // 64 MiB
  unsigned short* hidb   = (unsigned short*)(regA + 96 * MiB);  // 32 MiB
  unsigned short* ffnb   = (unsigned short*)(regA + 32 * MiB);  // gateup dead
  float* out = (float*)d_out;

  dim3 blk(256), gblk(512);
  cvt_bf<<<dim3(4096), blk, 0, stream>>>(X, Xb, (long)8388608);
  // Q|K fused: N=256 each, ldC=512, nx=4 -> 512 blocks (MI=2)
  gemm_tk<true, 2><<<dim3(512), gblk, 0, stream>>>(Xb, Qw, Kw, (void*)qkb, 256, 256, 2, 0, 512);
  // V: nx=16 -> 2048 blocks (MI=2); writes vb (b,t,2048)
  gemm_tk<true, 2><<<dim3(2048), gblk, 0, stream>>>(Xb, Vw, Vw, (void*)vb, 256, 2048, 4, 0, 2048);
  // attn reads vb directly (in-kernel transpose staging)
  attn_k<<<dim3(8, 256), gblk, 0, stream>>>(qkb, vb, cat);
  // O-proj -> bf16: MI=1 M-split (nx=2, mx=2) -> 512 blocks = 2/CU
  gemm_tk<true, 1><<<dim3(512), gblk, 0, stream>>>(cat, Ow, Ow, (void*)attnpb, 2048, 256, 1, 1, 256);
  // ln1: x1 = LN(Xb + attnpb) -> x1b only
  ln_k<false, true><<<dim3(8192), blk, 0, stream>>>(Xb, attnpb, g1, b1, (float*)nullptr, x1b);
  // gate|up fused: N=512 each, ldC=1024, nx=8 -> 1024 blocks (MI=2)
  gemm_tk<true, 2><<<dim3(1024), gblk, 0, stream>>>(x1b, Wg, Wu, (void*)gateup, 256, 512, 3, 0, 1024);
  silu_k<<<dim3(8192), blk, 0, stream>>>(gateup, hidb, (long)16777216);
  // down -> bf16: MI=1 M-split (nx=2, mx=2) -> 512 blocks = 2/CU
  gemm_tk<true, 1><<<dim3(512), gblk, 0, stream>>>(hidb, Wd, Wd, (void*)ffnb, 512, 256, 1, 1, 256);
  // ln2: out = LN(x1b + ffnb) -> fp32 d_out
  ln_k<true, false><<<dim3(8192), blk, 0, stream>>>(x1b, ffnb, g2, b2, out, (unsigned short*)nullptr);
}

// Round 14
// 454.988 us; speedup vs baseline: 1.2387x; 1.0223x over previous
//
#include <hip/hip_runtime.h>
#include <stdint.h>

// Problem constants: B=256, T=128, D=256, H=8, AE=32, DFF=512
#define DEVI static __device__ __forceinline__

typedef __attribute__((ext_vector_type(4))) float f32x4;
typedef __attribute__((ext_vector_type(8))) short bf8;     // 8 bf16 (MFMA A/B frag)
typedef __attribute__((ext_vector_type(4))) unsigned short u16x4;

DEVI unsigned short f2bf(float f) {
  unsigned u = __builtin_bit_cast(unsigned, f);
  u = (u + 0x7FFFu + ((u >> 16) & 1u)) >> 16;
  return (unsigned short)u;
}
DEVI float bf2f(unsigned short s) {
  return __builtin_bit_cast(float, ((unsigned)s) << 16);
}
DEVI unsigned cvt_pk_bf16(float lo, float hi) {
  unsigned r;
  asm("v_cvt_pk_bf16_f32 %0, %1, %2" : "=v"(r) : "v"(lo), "v"(hi));
  return r;
}
// swizzle for 256-B rows (attn ps): 16B granularity, 8 slots
DEVI int swz(int row) { return (((row >> 2) ^ row) & 7) << 4; }
// swizzle for 64-B rows (gemm As/Ws, attn vs): 16B granularity, 4 slots
DEVI int swz32(int row) { return (((row >> 1) ^ row) & 3) << 4; }

DEVI void gload16(const void* g, void* l) {
  __builtin_amdgcn_global_load_lds(
      (const __attribute__((address_space(1))) unsigned*)g,
      (__attribute__((address_space(3))) unsigned*)l, 16, 0, 0);
}

// ---------------------------------------------------------------------------
// Per-t batched GEMM: C[b-rows, t, n0+*] = sum_k A * Wsel
// Round 14: 2-deep W register prefetch. The K-loop is unrolled x2 with NAMED
// reg sets (rule #20: no runtime-indexed reg arrays) and compile-time As[0/1]
// indices. W(k+2) issued at tile k; cvt of W(k+1) (issued a full tile ago,
// landed) at tile k's end -> the per-tile cvt stall (~latency - MFMA) is gone.
// A staging (gload_lds, full-tile window) unchanged. Same k-order and cvt
// values => output bitwise identical to round-13 PASS. Requires nt even
// (all call sites: nt in {8,16,64}).
// MI=2: BM=256; MI=1: BM=128 with mx m-blocks. 1-D grid, XCD same-t grouping
// + two-weight fusion. 8 waves, BN=128, BK=32.
// ---------------------------------------------------------------------------
template<bool OUT_BF16, int MI>
__global__ __launch_bounds__(512, 4)
void gemm_tk(const unsigned short* __restrict__ A, const float* __restrict__ W0,
             const float* __restrict__ W1, void* __restrict__ C,
             int Ka, int N, int lognx, int logmx, int ldC)
{
  const int j = blockIdx.x;
  const int t = (j & 7) + 8 * (j >> (3 + lognx + logmx));
  const int nblk = (j >> 3) & ((1 << lognx) - 1);
  const int mblk = (j >> (3 + lognx)) & ((1 << logmx) - 1);
  const int n0blk = nblk * 128;
  const float* Wsel = (n0blk >= N) ? W1 : W0;
  const int n0w = (n0blk >= N) ? (n0blk - N) : n0blk;

  const int tid = threadIdx.x;
  const int lane = tid & 63;
  const int wv = tid >> 6;          // 0..7
  const int wrow = wv * (MI * 16);  // MI=2: 32 rows/wave; MI=1: 16

  __shared__ short As[2][MI * 128 * 32];  // [m][k] 64-B rows, swz32
  __shared__ short Ws[2][128 * 32];       // [n][k] 64-B rows, swz32; 2 x 8KB

  f32x4 acc[MI][8];
#pragma unroll
  for (int i = 0; i < MI; ++i)
#pragma unroll
    for (int jj = 0; jj < 8; ++jj) acc[i][jj] = f32x4{0.f, 0.f, 0.f, 0.f};

  const long ldA = 128L * Ka;
  const unsigned short* Ab = A + (long)t * Ka + (long)mblk * 128 * ldA;
  const float* Wb = Wsel + (long)t * Ka * N + n0w;

  const int n0 = (tid & 31) * 4;  // 4 consecutive n per thread (W staging)
  const int kp = tid >> 5;        // k-pair 0..15 (W staging)

  // ---- helpers (compile-time buf indices at every call site)
  auto wload = [&](int kt, f32x4& wlo, f32x4& whi) {
    const float* Wn = Wb + (long)kt * 32 * N;
    wlo = *(const f32x4*)(Wn + (long)(kp * 2) * N + n0);
    whi = *(const f32x4*)(Wn + (long)(kp * 2 + 1) * N + n0);
  };
  auto wcvt = [&](short* buf, const f32x4& wlo, const f32x4& whi) {
#pragma unroll
    for (int jj = 0; jj < 4; ++jj) {
      int n = n0 + jj;
      *(unsigned*)((char*)buf + n * 64 + ((kp * 4) ^ swz32(n))) =
          cvt_pk_bf16(wlo[jj], whi[jj]);
    }
  };
  auto astage = [&](int kt, short* buf) {
#pragma unroll
    for (int it = 0; it < MI; ++it) {
      int ci = tid + it * 512;            // 16B chunk id; m=ci>>2
      int m = ci >> 2, cb = (ci & 3) * 16;
      gload16((const char*)(Ab + (long)kt * 32 + (long)m * ldA) + (cb ^ swz32(m)),
              (char*)buf + ci * 16);
    }
  };
  auto mfma_tile = [&](const short* abuf, const short* wbuf) {
    const int kb2 = (lane >> 4) * 16;  // k-chunk byte offset
    bf8 a[MI];
#pragma unroll
    for (int mi = 0; mi < MI; ++mi) {
      const int m0 = wrow + mi * 16 + (lane & 15);
      a[mi] = *(const bf8*)((const char*)abuf + m0 * 64 + (kb2 ^ swz32(m0)));
    }
#pragma unroll
    for (int ni = 0; ni < 8; ++ni) {
      const int n = ni * 16 + (lane & 15);
      bf8 bfr = *(const bf8*)((const char*)wbuf + n * 64 + (kb2 ^ swz32(n)));
#pragma unroll
      for (int mi = 0; mi < MI; ++mi)
        acc[mi][ni] = __builtin_amdgcn_mfma_f32_16x16x32_bf16(a[mi], bfr, acc[mi][ni], 0, 0, 0);
    }
  };

  const int nt = Ka >> 5;  // even at all call sites (8/16/64)

  // ---- prologue: A(0) -> As[0]; W(0) -> setA, W(1) -> setB; cvt W(0) -> Ws[0]
  f32x4 wloA, whiA, wloB, whiB;
  astage(0, &As[0][0]);
  wload(0, wloA, whiA);
  wload(1, wloB, whiB);
  wcvt(&Ws[0][0], wloA, whiA);

  for (int kt = 0; kt < nt; kt += 2) {
    // ---- even phase: compute tile kt  (As[0], Ws[0])
    __syncthreads();  // A(kt)/Ws updates visible; all waves past prior reads
    if (kt + 2 < nt) wload(kt + 2, wloA, whiA);   // -> cvt at end of odd phase
    if (kt + 1 < nt) astage(kt + 1, &As[1][0]);
    mfma_tile(&As[0][0], &Ws[0][0]);
    wcvt(&Ws[1][0], wloB, whiB);                  // W(kt+1), issued >=1 tile ago

    // ---- odd phase: compute tile kt+1  (As[1], Ws[1])
    __syncthreads();
    if (kt + 3 < nt) wload(kt + 3, wloB, whiB);   // -> cvt at end of next even
    if (kt + 2 < nt) astage(kt + 2, &As[0][0]);
    mfma_tile(&As[1][0], &Ws[1][0]);
    if (kt + 2 < nt) wcvt(&Ws[0][0], wloA, whiA); // W(kt+2)
  }

  // epilogue: C/D layout col=lane&15, row=(lane>>4)*4+reg
#pragma unroll
  for (int mi = 0; mi < MI; ++mi)
#pragma unroll
    for (int ni = 0; ni < 8; ++ni)
#pragma unroll
      for (int r = 0; r < 4; ++r) {
        int m = mblk * 128 + wrow + mi * 16 + (lane >> 4) * 4 + r;
        int n = n0blk + ni * 16 + (lane & 15);
        long off = ((long)m * 128 + t) * ldC + n;
        float v = acc[mi][ni][r];
        if constexpr (OUT_BF16) reinterpret_cast<unsigned short*>(C)[off] = f2bf(v);
        else reinterpret_cast<float*>(C)[off] = v;
      }
}

// ---------------------------------------------------------------------------
// fp32 -> bf16 convert (X)
// ---------------------------------------------------------------------------
__global__ __launch_bounds__(256)
void cvt_bf(const float* __restrict__ in, unsigned short* __restrict__ out, long n)
{
  long i = ((long)blockIdx.x * 256 + threadIdx.x) * 8;
  if (i >= n) return;
  f32x4 a = *reinterpret_cast<const f32x4*>(in + i);
  f32x4 b = *reinterpret_cast<const f32x4*>(in + i + 4);
  u16x4 w0, w1;
#pragma unroll
  for (int j = 0; j < 4; ++j) { w0[j] = f2bf(a[j]); w1[j] = f2bf(b[j]); }
  *reinterpret_cast<u16x4*>(out + i) = w0;
  *reinterpret_cast<u16x4*>(out + i + 4) = w1;
}

// ---------------------------------------------------------------------------
// attn staging helper: write one thread's transposed V chunk into vs.
// (see round-13 header; LDS image matches the proven PV b128 read)
// ---------------------------------------------------------------------------
DEVI void stage_write_v(short* buf, f32x4 r0, f32x4 r1, int s2, int d0)
{
  const unsigned* a = reinterpret_cast<const unsigned*>(&r0);  // 4 words, 2 bf16 each
  const unsigned* c = reinterpret_cast<const unsigned*>(&r1);
#pragma unroll
  for (int j = 0; j < 8; ++j) {
    unsigned lo = (j & 1) ? (a[j >> 1] >> 16) : (a[j >> 1] & 0xFFFFu);
    unsigned hi = (j & 1) ? (c[j >> 1] >> 16) : (c[j >> 1] & 0xFFFFu);
    int d = d0 + j;
    *reinterpret_cast<unsigned*>(reinterpret_cast<char*>(buf) + d * 64 + ((4 * s2) ^ swz32(d))) =
        lo | (hi << 16);
  }
}

// ---------------------------------------------------------------------------
// Fused attention for one (b,h).  [= round-13 PASS verbatim]
// ---------------------------------------------------------------------------
__global__ __launch_bounds__(512, 4)
void attn_k(const unsigned short* __restrict__ qk, const unsigned short* __restrict__ vg,
            unsigned short* __restrict__ cat)
{
  const int h = blockIdx.x, b = blockIdx.y;
  const int tid = threadIdx.x, lane = tid & 63, wv = tid >> 6;
  const int wrow = wv * 16;          // 16 rows per wave

  __shared__ short ps[128 * 128];    // P [t][s] swizzled (256-B rows), 32KB
  __shared__ short vs[2][256 * 32];  // V chunk [d][s32] 64-B rows swz32, 2x16KB

  const long qkBase = ((long)b * 128) * 512 + h * 32;
  const long vgBase = ((long)b * 128) * 2048 + h * 256;  // + s*2048 + d
  const int kb_ = (lane >> 4) * 8;

  const int s2 = tid & 15;        // s = 2*s2, 2*s2+1
  const int d0 = (tid >> 4) * 8;  // 0..248

  // ---- issue chunk-0 loads (consumed after softmax, before first barrier)
  f32x4 r0, r1;
  {
    const unsigned short* src = vg + vgBase + (long)(2 * s2) * 2048 + d0;
    r0 = *reinterpret_cast<const f32x4*>(src);
    r1 = *reinterpret_cast<const f32x4*>(src + 2048);
  }

  // S = q k^T  (q/k frags straight from global; AE=32 = one MFMA K-step)
  f32x4 sacc[8];
#pragma unroll
  for (int c = 0; c < 8; ++c) sacc[c] = f32x4{0.f, 0.f, 0.f, 0.f};
  bf8 aq;
  {
    int row = wrow + (lane & 15);
    aq = *reinterpret_cast<const bf8*>(qk + qkBase + (long)row * 512 + kb_);
  }
#pragma unroll
  for (int ni = 0; ni < 8; ++ni) {
    int s = ni * 16 + (lane & 15);
    bf8 bk = *reinterpret_cast<const bf8*>(qk + qkBase + 256 + (long)s * 512 + kb_);
    sacc[ni] = __builtin_amdgcn_mfma_f32_16x16x32_bf16(aq, bk, sacc[ni], 0, 0, 0);
  }

  // wave-parallel softmax; P written unnormalized (divide after PV)
  const float scale = 0.17677669529663687f;  // 1/sqrt(32)
  float sinv[4];
#pragma unroll
  for (int r = 0; r < 4; ++r) {
    int row = wrow + (lane >> 4) * 4 + r;
    float vv[8];
    float mx = -1e30f;
#pragma unroll
    for (int c = 0; c < 8; ++c) { vv[c] = sacc[c][r] * scale; mx = fmaxf(mx, vv[c]); }
#pragma unroll
    for (int mm = 1; mm < 16; mm <<= 1) mx = fmaxf(mx, __shfl_xor(mx, mm, 64));
    float s_ = 0.f;
#pragma unroll
    for (int c = 0; c < 8; ++c) { vv[c] = __expf(vv[c] - mx); s_ += vv[c]; }
#pragma unroll
    for (int mm = 1; mm < 16; mm <<= 1) s_ += __shfl_xor(s_, mm, 64);
    sinv[r] = 1.0f / s_;
#pragma unroll
    for (int c = 0; c < 8; ++c) {
      int col = c * 16 + (lane & 15);
      int byte = row * 256 + ((col * 2) ^ swz(row));
      *reinterpret_cast<unsigned short*>(reinterpret_cast<char*>(ps) + byte) = f2bf(vv[c]);
    }
  }

  // write chunk 0 into vs[0] (loads had QK^T + softmax to land)
  stage_write_v(&vs[0][0], r0, r1, s2, d0);

  // PV over four 32-wide s-chunks, double-buffered LDS (T3 2-phase + T14).
  f32x4 oacc[16];
#pragma unroll
  for (int c = 0; c < 16; ++c) oacc[c] = f32x4{0.f, 0.f, 0.f, 0.f};

#pragma unroll 1
  for (int cs = 0; cs < 4; ++cs) {
    __syncthreads();  // vs[cs&1] published; all waves done reading vs[(cs+1)&1]
    if (cs < 3) {
      // issue next-chunk loads now; consumed after this chunk's MFMAs
      const unsigned short* src = vg + vgBase + (long)((cs + 1) * 32 + 2 * s2) * 2048 + d0;
      r0 = *reinterpret_cast<const f32x4*>(src);
      r1 = *reinterpret_cast<const f32x4*>(src + 2048);
    }
    const int kglob = cs * 32 + kb_;
    bf8 ap;
    {
      int row = wrow + (lane & 15);
      int byte = row * 256 + ((kglob * 2) ^ swz(row));
      ap = *reinterpret_cast<const bf8*>(reinterpret_cast<const char*>(ps) + byte);
    }
    __builtin_amdgcn_s_setprio(1);
#pragma unroll
    for (int c = 0; c < 16; ++c) {
      int d = c * 16 + (lane & 15);
      bf8 bv = *reinterpret_cast<const bf8*>(
          reinterpret_cast<const char*>(&vs[cs & 1][0]) + d * 64 + ((kb_ * 2) ^ swz32(d)));
      oacc[c] = __builtin_amdgcn_mfma_f32_16x16x32_bf16(ap, bv, oacc[c], 0, 0, 0);
    }
    __builtin_amdgcn_s_setprio(0);
    if (cs < 3) stage_write_v(&vs[(cs + 1) & 1][0], r0, r1, s2, d0);
  }

  // write cat[b,t,h*256+d] = out/row_sum (bf16)
#pragma unroll
  for (int c = 0; c < 16; ++c)
#pragma unroll
    for (int r = 0; r < 4; ++r) {
      int tt = wrow + (lane >> 4) * 4 + r;
      int d = c * 16 + (lane & 15);
      float v = oacc[c][r] * sinv[r];
      long off = ((long)b * 128 + tt) * 2048 + h * 256 + d;
      cat[off] = f2bf(v);
    }
}

// ---------------------------------------------------------------------------
// LayerNorm(a+b): a,b read as bf16; write fp32 (WF) and/or bf16 (WB).
// ---------------------------------------------------------------------------
template<bool WF, bool WB>
__global__ __launch_bounds__(256)
void ln_k(const unsigned short* __restrict__ a, const unsigned short* __restrict__ bsrc,
          const float* __restrict__ gamma, const float* __restrict__ beta,
          float* __restrict__ of, unsigned short* __restrict__ ob)
{
  const int row = blockIdx.x * 4 + (threadIdx.x >> 6);
  const int lane = threadIdx.x & 63;
  const long base = (long)row * 256 + lane * 4;
  u16x4 ua = *reinterpret_cast<const u16x4*>(a + base);
  u16x4 ub = *reinterpret_cast<const u16x4*>(bsrc + base);
  f32x4 x;
#pragma unroll
  for (int j = 0; j < 4; ++j) x[j] = bf2f(ua[j]) + bf2f(ub[j]);
  float s = x[0] + x[1] + x[2] + x[3];
  float s2 = x[0] * x[0] + x[1] * x[1] + x[2] * x[2] + x[3] * x[3];
#pragma unroll
  for (int mm = 1; mm < 64; mm <<= 1) { s += __shfl_xor(s, mm, 64); s2 += __shfl_xor(s2, mm, 64); }
  float mean = s * (1.f / 256.f);
  float var = fmaxf(s2 * (1.f / 256.f) - mean * mean, 0.f);
  float inv = rsqrtf(var + 1e-5f);
  f32x4 g = *reinterpret_cast<const f32x4*>(gamma + lane * 4);
  f32x4 be = *reinterpret_cast<const f32x4*>(beta + lane * 4);
  f32x4 y;
#pragma unroll
  for (int j = 0; j < 4; ++j) y[j] = (x[j] - mean) * inv * g[j] + be[j];
  if constexpr (WF) *reinterpret_cast<f32x4*>(of + base) = y;
  if constexpr (WB) {
    u16x4 w;
#pragma unroll
    for (int j = 0; j < 4; ++j) w[j] = f2bf(y[j]);
    *reinterpret_cast<u16x4*>(ob + base) = w;
  }
}

// ---------------------------------------------------------------------------
// hidden = silu(gate) * up, reading the fused gateup buffer.
// ---------------------------------------------------------------------------
__global__ __launch_bounds__(256)
void silu_k(const unsigned short* __restrict__ gu, unsigned short* __restrict__ o, long n)
{
  long i = ((long)blockIdx.x * 256 + threadIdx.x) * 8;
  if (i >= n) return;
  long r = i >> 9;
  int f = (int)(i & 511);
  const unsigned short* g = gu + r * 1024 + f;
  const unsigned short* u = g + 512;
  u16x4 g0 = *reinterpret_cast<const u16x4*>(g);
  u16x4 g1 = *reinterpret_cast<const u16x4*>(g + 4);
  u16x4 u0 = *reinterpret_cast<const u16x4*>(u);
  u16x4 u1 = *reinterpret_cast<const u16x4*>(u + 4);
  u16x4 o0, o1;
#pragma unroll
  for (int j = 0; j < 4; ++j) {
    float gg = bf2f(g0[j]), uu = bf2f(u0[j]);
    o0[j] = f2bf(gg / (1.f + __expf(-gg)) * uu);
    gg = bf2f(g1[j]); uu = bf2f(u1[j]);
    o1[j] = f2bf(gg / (1.f + __expf(-gg)) * uu);
  }
  *reinterpret_cast<u16x4*>(o + i) = o0;
  *reinterpret_cast<u16x4*>(o + i + 4) = o1;
}

// ---------------------------------------------------------------------------
// Workspace (304 MiB, lifetime reuse; trans_v/vT eliminated):
//   [0,16) Xb   [16,48) qkb
//   regA @48MiB (128): vb(128, dead after attn) -> attnpb@0(16)|x1b@16(16)|
//                      gateup@32(64, dead after silu)|hid@96(32)|ffnb@32(16)
//   regB @176MiB (128): cat(128, dead after O-proj)
// ---------------------------------------------------------------------------
extern "C" void kernel_launch(void* const* d_in, const int* in_sizes, int n_in,
                              void* d_out, int out_size, void* d_ws, size_t ws_size,
                              hipStream_t stream)
{
  const float* X  = (const float*)d_in[0];
  const float* Qw = (const float*)d_in[1];
  const float* Kw = (const float*)d_in[2];
  const float* Vw = (const float*)d_in[3];
  const float* Ow = (const float*)d_in[4];
  const float* Wg = (const float*)d_in[5];
  const float* Wu = (const float*)d_in[6];
  const float* Wd = (const float*)d_in[7];
  const float* g1 = (const float*)d_in[8];
  const float* b1 = (const float*)d_in[9];
  const float* g2 = (const float*)d_in[10];
  const float* b2 = (const float*)d_in[11];

  char* ws = (char*)d_ws;
  const size_t MiB = 1048576;
  unsigned short* Xb  = (unsigned short*)(ws);
  unsigned short* qkb = (unsigned short*)(ws + 16 * MiB);
  char* regA = ws + 48 * MiB;    // 128 MiB
  char* regB = regA + 128 * MiB; // 128 MiB

  unsigned short* vb     = (unsigned short*)regA;           // dead after attn_k
  unsigned short* cat    = (unsigned short*)regB;           // dead after O-proj
  unsigned short* attnpb = (unsigned short*)(regA);         // O-proj out (vb dead)
  unsigned short* x1b    = (unsigned short*)(regA + 16 * MiB);
  unsigned short* gateup = (unsigned short*)(regA + 32 * MiB);  // 64 MiB
  unsigned short* hidb   = (unsigned short*)(regA + 96 * MiB);  // 32 MiB
  unsigned short* ffnb   = (unsigned short*)(regA + 32 * MiB);  // gateup dead
  float* out = (float*)d_out;

  dim3 blk(256), gblk(512);
  cvt_bf<<<dim3(4096), blk, 0, stream>>>(X, Xb, (long)8388608);
  // Q|K fused: N=256 each, ldC=512, nx=4 -> 512 blocks (MI=2)
  gemm_tk<true, 2><<<dim3(512), gblk, 0, stream>>>(Xb, Qw, Kw, (void*)qkb, 256, 256, 2, 0, 512);
  // V: nx=16 -> 2048 blocks (MI=2); writes vb (b,t,2048)
  gemm_tk<true, 2><<<dim3(2048), gblk, 0, stream>>>(Xb, Vw, Vw, (void*)vb, 256, 2048, 4, 0, 2048);
  // attn reads vb directly (in-kernel transpose staging)
  attn_k<<<dim3(8, 256), gblk, 0, stream>>>(qkb, vb, cat);
  // O-proj -> bf16: MI=1 M-split (nx=2, mx=2) -> 512 blocks = 2/CU
  gemm_tk<true, 1><<<dim3(512), gblk, 0, stream>>>(cat, Ow, Ow, (void*)attnpb, 2048, 256, 1, 1, 256);
  // ln1: x1 = LN(Xb + attnpb) -> x1b only
  ln_k<false, true><<<dim3(8192), blk, 0, stream>>>(Xb, attnpb, g1, b1, (float*)nullptr, x1b);
  // gate|up fused: N=512 each, ldC=1024, nx=8 -> 1024 blocks (MI=2)
  gemm_tk<true, 2><<<dim3(1024), gblk, 0, stream>>>(x1b, Wg, Wu, (void*)gateup, 256, 512, 3, 0, 1024);
  silu_k<<<dim3(8192), blk, 0, stream>>>(gateup, hidb, (long)16777216);
  // down -> bf16: MI=1 M-split (nx=2, mx=2) -> 512 blocks = 2/CU
  gemm_tk<true, 1><<<dim3(512), gblk, 0, stream>>>(hidb, Wd, Wd, (void*)ffnb, 512, 256, 1, 1, 256);
  // ln2: out = LN(x1b + ffnb) -> fp32 d_out
  ln_k<true, false><<<dim3(8192), blk, 0, stream>>>(x1b, ffnb, g2, b2, out, (unsigned short*)nullptr);
}

// Round 15
// 445.123 us; speedup vs baseline: 1.2662x; 1.0222x over previous
//
#include <hip/hip_runtime.h>
#include <stdint.h>

// Problem constants: B=256, T=128, D=256, H=8, AE=32, DFF=512
#define DEVI static __device__ __forceinline__

typedef __attribute__((ext_vector_type(4))) float f32x4;
typedef __attribute__((ext_vector_type(8))) short bf8;     // 8 bf16 (MFMA A/B frag)
typedef __attribute__((ext_vector_type(4))) unsigned short u16x4;
typedef __attribute__((ext_vector_type(4))) unsigned int u32x4;

DEVI unsigned short f2bf(float f) {
  unsigned u = __builtin_bit_cast(unsigned, f);
  u = (u + 0x7FFFu + ((u >> 16) & 1u)) >> 16;
  return (unsigned short)u;
}
DEVI float bf2f(unsigned short s) {
  return __builtin_bit_cast(float, ((unsigned)s) << 16);
}
DEVI unsigned cvt_pk_bf16(float lo, float hi) {
  unsigned r;
  asm("v_cvt_pk_bf16_f32 %0, %1, %2" : "=v"(r) : "v"(lo), "v"(hi));
  return r;
}
// swizzle for 256-B rows (attn ps): 16B granularity, 8 slots
DEVI int swz(int row) { return (((row >> 2) ^ row) & 7) << 4; }
// swizzle for 64-B rows (gemm As/Ws, attn vs): 16B granularity, 4 slots
DEVI int swz32(int row) { return (((row >> 1) ^ row) & 3) << 4; }

DEVI void gload16(const void* g, void* l) {
  __builtin_amdgcn_global_load_lds(
      (const __attribute__((address_space(1))) unsigned*)g,
      (__attribute__((address_space(3))) unsigned*)l, 16, 0, 0);
}

// ---------------------------------------------------------------------------
// Per-t batched GEMM: C[b-rows, t, n0+*] = sum_k A * Wsel
// Round 14 structure (2-deep W reg prefetch, x2-unrolled K-loop, named regs).
// Round 15: SILU mode — A-staging computes hid = silu(gate)*up from the
// gateup buffer during staging (reg-staged: load at phase top, silu+pack+
// ds_write after the MFMA cluster; same hazard structure as Ws). Values match
// the old silu_k bit-for-bit (same expression, RNE pack) => output bitwise
// identical; the separate silu kernel + hid buffer are eliminated.
// MI=2: BM=256; MI=1: BM=128 with mx m-blocks. 1-D grid, XCD same-t grouping
// + two-weight fusion. 8 waves, BN=128, BK=32. nt even at all call sites.
// ---------------------------------------------------------------------------
template<bool OUT_BF16, int MI, bool SILU>
__global__ __launch_bounds__(512, 4)
void gemm_tk(const unsigned short* __restrict__ A, const float* __restrict__ W0,
             const float* __restrict__ W1, void* __restrict__ C,
             int Ka, int N, int lognx, int logmx, int ldC)
{
  const int j = blockIdx.x;
  const int t = (j & 7) + 8 * (j >> (3 + lognx + logmx));
  const int nblk = (j >> 3) & ((1 << lognx) - 1);
  const int mblk = (j >> (3 + lognx)) & ((1 << logmx) - 1);
  const int n0blk = nblk * 128;
  const float* Wsel = (n0blk >= N) ? W1 : W0;
  const int n0w = (n0blk >= N) ? (n0blk - N) : n0blk;

  const int tid = threadIdx.x;
  const int lane = tid & 63;
  const int wv = tid >> 6;          // 0..7
  const int wrow = wv * (MI * 16);  // MI=2: 32 rows/wave; MI=1: 16

  __shared__ short As[2][MI * 128 * 32];  // [m][k] 64-B rows, swz32
  __shared__ short Ws[2][128 * 32];       // [n][k] 64-B rows, swz32; 2 x 8KB

  f32x4 acc[MI][8];
#pragma unroll
  for (int i = 0; i < MI; ++i)
#pragma unroll
    for (int jj = 0; jj < 8; ++jj) acc[i][jj] = f32x4{0.f, 0.f, 0.f, 0.f};

  const long ldA = 128L * Ka;
  const unsigned short* Ab = A + (long)t * Ka + (long)mblk * 128 * ldA;
  const float* Wb = Wsel + (long)t * Ka * N + n0w;

  const int n0 = (tid & 31) * 4;  // 4 consecutive n per thread (W staging)
  const int kp = tid >> 5;        // k-pair 0..15 (W staging)

  // ---- helpers (compile-time buf indices at every call site)
  auto wload = [&](int kt, f32x4& wlo, f32x4& whi) {
    const float* Wn = Wb + (long)kt * 32 * N;
    wlo = *(const f32x4*)(Wn + (long)(kp * 2) * N + n0);
    whi = *(const f32x4*)(Wn + (long)(kp * 2 + 1) * N + n0);
  };
  auto wcvt = [&](short* buf, const f32x4& wlo, const f32x4& whi) {
#pragma unroll
    for (int jj = 0; jj < 4; ++jj) {
      int n = n0 + jj;
      *(unsigned*)((char*)buf + n * 64 + ((kp * 4) ^ swz32(n))) =
          cvt_pk_bf16(wlo[jj], whi[jj]);
    }
  };
  // mode 0: direct global->LDS (pre-swizzled source)
  auto astage = [&](int kt, short* buf) {
#pragma unroll
    for (int it = 0; it < MI; ++it) {
      int ci = tid + it * 512;            // 16B chunk id; m=ci>>2
      int m = ci >> 2, cb = (ci & 3) * 16;
      gload16((const char*)(Ab + (long)kt * 32 + (long)m * ldA) + (cb ^ swz32(m)),
              (char*)buf + ci * 16);
    }
  };
  // SILU mode (MI=1): A = gateup[(b*128+t)*1024 + f], gate at f, up at 512+f
  const unsigned short* gub = A + ((long)mblk * 128 * 128 + t) * 1024;
  auto aload_silu = [&](int kt, bf8& g8, bf8& u8) {
    const int m = tid >> 2, cb8 = (tid & 3) * 8;
    const long base = (long)m * 131072 + kt * 32 + cb8;
    g8 = *(const bf8*)(gub + base);
    u8 = *(const bf8*)(gub + base + 512);
  };
  auto awrite_silu = [&](short* buf, const bf8& g8, const bf8& u8) {
    const int m = tid >> 2, cbB = (tid & 3) * 16;
    float h[8];
#pragma unroll
    for (int jj = 0; jj < 8; ++jj) {
      float gg = bf2f((unsigned short)g8[jj]);
      float uu = bf2f((unsigned short)u8[jj]);
      h[jj] = gg / (1.f + __expf(-gg)) * uu;   // verbatim silu_k expression
    }
    u32x4 w;
#pragma unroll
    for (int p = 0; p < 4; ++p) w[p] = cvt_pk_bf16(h[2 * p], h[2 * p + 1]);
    *(u32x4*)((char*)buf + m * 64 + (cbB ^ swz32(m))) = w;
  };
  auto mfma_tile = [&](const short* abuf, const short* wbuf) {
    const int kb2 = (lane >> 4) * 16;  // k-chunk byte offset
    bf8 a[MI];
#pragma unroll
    for (int mi = 0; mi < MI; ++mi) {
      const int m0 = wrow + mi * 16 + (lane & 15);
      a[mi] = *(const bf8*)((const char*)abuf + m0 * 64 + (kb2 ^ swz32(m0)));
    }
#pragma unroll
    for (int ni = 0; ni < 8; ++ni) {
      const int n = ni * 16 + (lane & 15);
      bf8 bfr = *(const bf8*)((const char*)wbuf + n * 64 + (kb2 ^ swz32(n)));
#pragma unroll
      for (int mi = 0; mi < MI; ++mi)
        acc[mi][ni] = __builtin_amdgcn_mfma_f32_16x16x32_bf16(a[mi], bfr, acc[mi][ni], 0, 0, 0);
    }
  };

  const int nt = Ka >> 5;  // even at all call sites (8/16/64)

  // ---- prologue: A(0) -> As[0]; W(0) -> setA, W(1) -> setB; cvt W(0) -> Ws[0]
  f32x4 wloA, whiA, wloB, whiB;
  if constexpr (SILU) {
    bf8 g0, u0;
    aload_silu(0, g0, u0);
    awrite_silu(&As[0][0], g0, u0);
  } else {
    astage(0, &As[0][0]);
  }
  wload(0, wloA, whiA);
  wload(1, wloB, whiB);
  wcvt(&Ws[0][0], wloA, whiA);

  for (int kt = 0; kt < nt; kt += 2) {
    // ---- even phase: compute tile kt  (As[0], Ws[0])
    __syncthreads();  // A(kt)/Ws updates visible; all waves past prior reads
    bf8 gE, uE;
    if (kt + 2 < nt) wload(kt + 2, wloA, whiA);   // -> cvt at end of odd phase
    if (kt + 1 < nt) {
      if constexpr (SILU) aload_silu(kt + 1, gE, uE);
      else astage(kt + 1, &As[1][0]);
    }
    mfma_tile(&As[0][0], &Ws[0][0]);
    wcvt(&Ws[1][0], wloB, whiB);                  // W(kt+1), issued >=1 tile ago
    if constexpr (SILU) { if (kt + 1 < nt) awrite_silu(&As[1][0], gE, uE); }

    // ---- odd phase: compute tile kt+1  (As[1], Ws[1])
    __syncthreads();
    bf8 gO, uO;
    if (kt + 3 < nt) wload(kt + 3, wloB, whiB);   // -> cvt at end of next even
    if (kt + 2 < nt) {
      if constexpr (SILU) aload_silu(kt + 2, gO, uO);
      else astage(kt + 2, &As[0][0]);
    }
    mfma_tile(&As[1][0], &Ws[1][0]);
    if (kt + 2 < nt) wcvt(&Ws[0][0], wloA, whiA); // W(kt+2)
    if constexpr (SILU) { if (kt + 2 < nt) awrite_silu(&As[0][0], gO, uO); }
  }

  // epilogue: C/D layout col=lane&15, row=(lane>>4)*4+reg
#pragma unroll
  for (int mi = 0; mi < MI; ++mi)
#pragma unroll
    for (int ni = 0; ni < 8; ++ni)
#pragma unroll
      for (int r = 0; r < 4; ++r) {
        int m = mblk * 128 + wrow + mi * 16 + (lane >> 4) * 4 + r;
        int n = n0blk + ni * 16 + (lane & 15);
        long off = ((long)m * 128 + t) * ldC + n;
        float v = acc[mi][ni][r];
        if constexpr (OUT_BF16) reinterpret_cast<unsigned short*>(C)[off] = f2bf(v);
        else reinterpret_cast<float*>(C)[off] = v;
      }
}

// ---------------------------------------------------------------------------
// fp32 -> bf16 convert (X)
// ---------------------------------------------------------------------------
__global__ __launch_bounds__(256)
void cvt_bf(const float* __restrict__ in, unsigned short* __restrict__ out, long n)
{
  long i = ((long)blockIdx.x * 256 + threadIdx.x) * 8;
  if (i >= n) return;
  f32x4 a = *reinterpret_cast<const f32x4*>(in + i);
  f32x4 b = *reinterpret_cast<const f32x4*>(in + i + 4);
  u16x4 w0, w1;
#pragma unroll
  for (int j = 0; j < 4; ++j) { w0[j] = f2bf(a[j]); w1[j] = f2bf(b[j]); }
  *reinterpret_cast<u16x4*>(out + i) = w0;
  *reinterpret_cast<u16x4*>(out + i + 4) = w1;
}

// ---------------------------------------------------------------------------
// attn staging helper: write one thread's transposed V chunk into vs.
// ---------------------------------------------------------------------------
DEVI void stage_write_v(short* buf, f32x4 r0, f32x4 r1, int s2, int d0)
{
  const unsigned* a = reinterpret_cast<const unsigned*>(&r0);  // 4 words, 2 bf16 each
  const unsigned* c = reinterpret_cast<const unsigned*>(&r1);
#pragma unroll
  for (int j = 0; j < 8; ++j) {
    unsigned lo = (j & 1) ? (a[j >> 1] >> 16) : (a[j >> 1] & 0xFFFFu);
    unsigned hi = (j & 1) ? (c[j >> 1] >> 16) : (c[j >> 1] & 0xFFFFu);
    int d = d0 + j;
    *reinterpret_cast<unsigned*>(reinterpret_cast<char*>(buf) + d * 64 + ((4 * s2) ^ swz32(d))) =
        lo | (hi << 16);
  }
}

// ---------------------------------------------------------------------------
// Fused attention for one (b,h).  [= round-13/14 PASS verbatim]
// ---------------------------------------------------------------------------
__global__ __launch_bounds__(512, 4)
void attn_k(const unsigned short* __restrict__ qk, const unsigned short* __restrict__ vg,
            unsigned short* __restrict__ cat)
{
  const int h = blockIdx.x, b = blockIdx.y;
  const int tid = threadIdx.x, lane = tid & 63, wv = tid >> 6;
  const int wrow = wv * 16;          // 16 rows per wave

  __shared__ short ps[128 * 128];    // P [t][s] swizzled (256-B rows), 32KB
  __shared__ short vs[2][256 * 32];  // V chunk [d][s32] 64-B rows swz32, 2x16KB

  const long qkBase = ((long)b * 128) * 512 + h * 32;
  const long vgBase = ((long)b * 128) * 2048 + h * 256;  // + s*2048 + d
  const int kb_ = (lane >> 4) * 8;

  const int s2 = tid & 15;        // s = 2*s2, 2*s2+1
  const int d0 = (tid >> 4) * 8;  // 0..248

  // ---- issue chunk-0 loads (consumed after softmax, before first barrier)
  f32x4 r0, r1;
  {
    const unsigned short* src = vg + vgBase + (long)(2 * s2) * 2048 + d0;
    r0 = *reinterpret_cast<const f32x4*>(src);
    r1 = *reinterpret_cast<const f32x4*>(src + 2048);
  }

  // S = q k^T  (q/k frags straight from global; AE=32 = one MFMA K-step)
  f32x4 sacc[8];
#pragma unroll
  for (int c = 0; c < 8; ++c) sacc[c] = f32x4{0.f, 0.f, 0.f, 0.f};
  bf8 aq;
  {
    int row = wrow + (lane & 15);
    aq = *reinterpret_cast<const bf8*>(qk + qkBase + (long)row * 512 + kb_);
  }
#pragma unroll
  for (int ni = 0; ni < 8; ++ni) {
    int s = ni * 16 + (lane & 15);
    bf8 bk = *reinterpret_cast<const bf8*>(qk + qkBase + 256 + (long)s * 512 + kb_);
    sacc[ni] = __builtin_amdgcn_mfma_f32_16x16x32_bf16(aq, bk, sacc[ni], 0, 0, 0);
  }

  // wave-parallel softmax; P written unnormalized (divide after PV)
  const float scale = 0.17677669529663687f;  // 1/sqrt(32)
  float sinv[4];
#pragma unroll
  for (int r = 0; r < 4; ++r) {
    int row = wrow + (lane >> 4) * 4 + r;
    float vv[8];
    float mx = -1e30f;
#pragma unroll
    for (int c = 0; c < 8; ++c) { vv[c] = sacc[c][r] * scale; mx = fmaxf(mx, vv[c]); }
#pragma unroll
    for (int mm = 1; mm < 16; mm <<= 1) mx = fmaxf(mx, __shfl_xor(mx, mm, 64));
    float s_ = 0.f;
#pragma unroll
    for (int c = 0; c < 8; ++c) { vv[c] = __expf(vv[c] - mx); s_ += vv[c]; }
#pragma unroll
    for (int mm = 1; mm < 16; mm <<= 1) s_ += __shfl_xor(s_, mm, 64);
    sinv[r] = 1.0f / s_;
#pragma unroll
    for (int c = 0; c < 8; ++c) {
      int col = c * 16 + (lane & 15);
      int byte = row * 256 + ((col * 2) ^ swz(row));
      *reinterpret_cast<unsigned short*>(reinterpret_cast<char*>(ps) + byte) = f2bf(vv[c]);
    }
  }

  // write chunk 0 into vs[0] (loads had QK^T + softmax to land)
  stage_write_v(&vs[0][0], r0, r1, s2, d0);

  // PV over four 32-wide s-chunks, double-buffered LDS (T3 2-phase + T14).
  f32x4 oacc[16];
#pragma unroll
  for (int c = 0; c < 16; ++c) oacc[c] = f32x4{0.f, 0.f, 0.f, 0.f};

#pragma unroll 1
  for (int cs = 0; cs < 4; ++cs) {
    __syncthreads();  // vs[cs&1] published; all waves done reading vs[(cs+1)&1]
    if (cs < 3) {
      // issue next-chunk loads now; consumed after this chunk's MFMAs
      const unsigned short* src = vg + vgBase + (long)((cs + 1) * 32 + 2 * s2) * 2048 + d0;
      r0 = *reinterpret_cast<const f32x4*>(src);
      r1 = *reinterpret_cast<const f32x4*>(src + 2048);
    }
    const int kglob = cs * 32 + kb_;
    bf8 ap;
    {
      int row = wrow + (lane & 15);
      int byte = row * 256 + ((kglob * 2) ^ swz(row));
      ap = *reinterpret_cast<const bf8*>(reinterpret_cast<const char*>(ps) + byte);
    }
    __builtin_amdgcn_s_setprio(1);
#pragma unroll
    for (int c = 0; c < 16; ++c) {
      int d = c * 16 + (lane & 15);
      bf8 bv = *reinterpret_cast<const bf8*>(
          reinterpret_cast<const char*>(&vs[cs & 1][0]) + d * 64 + ((kb_ * 2) ^ swz32(d)));
      oacc[c] = __builtin_amdgcn_mfma_f32_16x16x32_bf16(ap, bv, oacc[c], 0, 0, 0);
    }
    __builtin_amdgcn_s_setprio(0);
    if (cs < 3) stage_write_v(&vs[(cs + 1) & 1][0], r0, r1, s2, d0);
  }

  // write cat[b,t,h*256+d] = out/row_sum (bf16)
#pragma unroll
  for (int c = 0; c < 16; ++c)
#pragma unroll
    for (int r = 0; r < 4; ++r) {
      int tt = wrow + (lane >> 4) * 4 + r;
      int d = c * 16 + (lane & 15);
      float v = oacc[c][r] * sinv[r];
      long off = ((long)b * 128 + tt) * 2048 + h * 256 + d;
      cat[off] = f2bf(v);
    }
}

// ---------------------------------------------------------------------------
// LayerNorm(a+b): a,b read as bf16; write fp32 (WF) and/or bf16 (WB).
// ---------------------------------------------------------------------------
template<bool WF, bool WB>
__global__ __launch_bounds__(256)
void ln_k(const unsigned short* __restrict__ a, const unsigned short* __restrict__ bsrc,
          const float* __restrict__ gamma, const float* __restrict__ beta,
          float* __restrict__ of, unsigned short* __restrict__ ob)
{
  const int row = blockIdx.x * 4 + (threadIdx.x >> 6);
  const int lane = threadIdx.x & 63;
  const long base = (long)row * 256 + lane * 4;
  u16x4 ua = *reinterpret_cast<const u16x4*>(a + base);
  u16x4 ub = *reinterpret_cast<const u16x4*>(bsrc + base);
  f32x4 x;
#pragma unroll
  for (int j = 0; j < 4; ++j) x[j] = bf2f(ua[j]) + bf2f(ub[j]);
  float s = x[0] + x[1] + x[2] + x[3];
  float s2 = x[0] * x[0] + x[1] * x[1] + x[2] * x[2] + x[3] * x[3];
#pragma unroll
  for (int mm = 1; mm < 64; mm <<= 1) { s += __shfl_xor(s, mm, 64); s2 += __shfl_xor(s2, mm, 64); }
  float mean = s * (1.f / 256.f);
  float var = fmaxf(s2 * (1.f / 256.f) - mean * mean, 0.f);
  float inv = rsqrtf(var + 1e-5f);
  f32x4 g = *reinterpret_cast<const f32x4*>(gamma + lane * 4);
  f32x4 be = *reinterpret_cast<const f32x4*>(beta + lane * 4);
  f32x4 y;
#pragma unroll
  for (int j = 0; j < 4; ++j) y[j] = (x[j] - mean) * inv * g[j] + be[j];
  if constexpr (WF) *reinterpret_cast<f32x4*>(of + base) = y;
  if constexpr (WB) {
    u16x4 w;
#pragma unroll
    for (int j = 0; j < 4; ++j) w[j] = f2bf(y[j]);
    *reinterpret_cast<u16x4*>(ob + base) = w;
  }
}

// ---------------------------------------------------------------------------
// Workspace (304 MiB, lifetime reuse; silu/hid ELIMINATED this round):
//   [0,16) Xb   [16,48) qkb
//   regA @48MiB (128): vb(128, dead after attn) -> attnpb@0(16)|x1b@16(16)|
//                      gateup@32(64, read by down)|ffnb@96(16)
//   regB @176MiB (128): cat(128, dead after O-proj)
// ---------------------------------------------------------------------------
extern "C" void kernel_launch(void* const* d_in, const int* in_sizes, int n_in,
                              void* d_out, int out_size, void* d_ws, size_t ws_size,
                              hipStream_t stream)
{
  const float* X  = (const float*)d_in[0];
  const float* Qw = (const float*)d_in[1];
  const float* Kw = (const float*)d_in[2];
  const float* Vw = (const float*)d_in[3];
  const float* Ow = (const float*)d_in[4];
  const float* Wg = (const float*)d_in[5];
  const float* Wu = (const float*)d_in[6];
  const float* Wd = (const float*)d_in[7];
  const float* g1 = (const float*)d_in[8];
  const float* b1 = (const float*)d_in[9];
  const float* g2 = (const float*)d_in[10];
  const float* b2 = (const float*)d_in[11];

  char* ws = (char*)d_ws;
  const size_t MiB = 1048576;
  unsigned short* Xb  = (unsigned short*)(ws);
  unsigned short* qkb = (unsigned short*)(ws + 16 * MiB);
  char* regA = ws + 48 * MiB;    // 128 MiB
  char* regB = regA + 128 * MiB; // 128 MiB

  unsigned short* vb     = (unsigned short*)regA;           // dead after attn_k
  unsigned short* cat    = (unsigned short*)regB;           // dead after O-proj
  unsigned short* attnpb = (unsigned short*)(regA);         // O-proj out (vb dead)
  unsigned short* x1b    = (unsigned short*)(regA + 16 * MiB);
  unsigned short* gateup = (unsigned short*)(regA + 32 * MiB);  // 64 MiB
  unsigned short* ffnb   = (unsigned short*)(regA + 96 * MiB);  // 16 MiB
  float* out = (float*)d_out;

  dim3 blk(256), gblk(512);
  cvt_bf<<<dim3(4096), blk, 0, stream>>>(X, Xb, (long)8388608);
  // Q|K fused: N=256 each, ldC=512, nx=4 -> 512 blocks (MI=2)
  gemm_tk<true, 2, false><<<dim3(512), gblk, 0, stream>>>(Xb, Qw, Kw, (void*)qkb, 256, 256, 2, 0, 512);
  // V: nx=16 -> 2048 blocks (MI=2); writes vb (b,t,2048)
  gemm_tk<true, 2, false><<<dim3(2048), gblk, 0, stream>>>(Xb, Vw, Vw, (void*)vb, 256, 2048, 4, 0, 2048);
  // attn reads vb directly (in-kernel transpose staging)
  attn_k<<<dim3(8, 256), gblk, 0, stream>>>(qkb, vb, cat);
  // O-proj -> bf16: MI=1 M-split (nx=2, mx=2) -> 512 blocks = 2/CU
  gemm_tk<true, 1, false><<<dim3(512), gblk, 0, stream>>>(cat, Ow, Ow, (void*)attnpb, 2048, 256, 1, 1, 256);
  // ln1: x1 = LN(Xb + attnpb) -> x1b only
  ln_k<false, true><<<dim3(8192), blk, 0, stream>>>(Xb, attnpb, g1, b1, (float*)nullptr, x1b);
  // gate|up fused: N=512 each, ldC=1024, nx=8 -> 1024 blocks (MI=2)
  gemm_tk<true, 2, false><<<dim3(1024), gblk, 0, stream>>>(x1b, Wg, Wu, (void*)gateup, 256, 512, 3, 0, 1024);
  // down -> bf16 with FUSED silu A-staging (reads gateup; silu+hid eliminated)
  gemm_tk<true, 1, true><<<dim3(512), gblk, 0, stream>>>(gateup, Wd, Wd, (void*)ffnb, 512, 256, 1, 1, 256);
  // ln2: out = LN(x1b + ffnb) -> fp32 d_out
  ln_k<true, false><<<dim3(8192), blk, 0, stream>>>(x1b, ffnb, g2, b2, out, (unsigned short*)nullptr);
}